// Round 1
// baseline (413.498 us; speedup 1.0000x reference)
//
#include <hip/hip_runtime.h>
#include <stdint.h>

typedef __attribute__((ext_vector_type(8))) short short8;
typedef __attribute__((ext_vector_type(4))) short short4v;
typedef __attribute__((ext_vector_type(4))) float f32x4;

static __device__ __forceinline__ unsigned short f2b(float f) {
  unsigned int u = __builtin_bit_cast(unsigned int, f);
  u += 0x7fffu + ((u >> 16) & 1u);
  return (unsigned short)(u >> 16);
}
static __device__ __forceinline__ float b2f(unsigned short b) {
  unsigned int u = ((unsigned int)b) << 16;
  return __builtin_bit_cast(float, u);
}

#define GLD16(gp, lp)                                                          \
  __builtin_amdgcn_global_load_lds(                                            \
      (const __attribute__((address_space(1))) void*)(gp),                     \
      (__attribute__((address_space(3))) void*)(lp), 16, 0, 0)

// ---------------- fp32 -> bf16 convert (float4 -> 4x bf16) ----------------
__global__ void cvt_kernel(const float* __restrict__ src,
                           unsigned short* __restrict__ dst, int n4) {
  int i = blockIdx.x * 256 + threadIdx.x;
  if (i >= n4) return;
  float4 v = reinterpret_cast<const float4*>(src)[i];
  short4v o;
  o.x = (short)f2b(v.x);
  o.y = (short)f2b(v.y);
  o.z = (short)f2b(v.z);
  o.w = (short)f2b(v.w);
  reinterpret_cast<short4v*>(dst)[i] = o;
}

// ---------------- projection GEMM: C[row][col] = X[row][:] . W[col][:] -----
// X: [8192][768] bf16 row-major. W: [NC][768] bf16 row-major (pre-concat).
// MODE 0 (query): NC=1536, mats {0: qd -> Qc[..][0:64], 1: q+bq -> Qc[..][64:128]}
// MODE 1 (key):   NC=2304, mats {0: kd -> Kc lo, 1: k+bk -> Kc hi, 2: v+bv -> Vt}
// Qc/Kc: [96][1024][128] bf16.  Vt: [96][64][1024] bf16 (transposed).
template <int MODE>
__global__ __launch_bounds__(256) void proj_kernel(
    const unsigned short* __restrict__ X, const unsigned short* __restrict__ W,
    const float* __restrict__ b1, const float* __restrict__ b2,
    unsigned short* __restrict__ outC, unsigned short* __restrict__ outV) {
  __shared__ __align__(16) short lds[2][2][128 * 32];  // [buf][A/B][8KB]
  const int row0 = blockIdx.x * 128;
  const int col0 = blockIdx.y * 128;
  const int lane = threadIdx.x & 63;
  const int w = threadIdx.x >> 6;
  const int wr = w >> 1, wc = w & 1;
  const int l15 = lane & 15, l4 = lane >> 4;

  f32x4 acc[4][4];
#pragma unroll
  for (int i = 0; i < 4; ++i)
#pragma unroll
    for (int j = 0; j < 4; ++j) acc[i][j] = (f32x4){0.f, 0.f, 0.f, 0.f};

  auto stage = [&](int buf, int k0) {
#pragma unroll
    for (int iss = 0; iss < 2; ++iss) {
      int c = iss * 256 + w * 64 + lane;
      const unsigned short* gp =
          X + (size_t)(row0 + (c >> 2)) * 768 + k0 + (c & 3) * 8;
      GLD16(gp, (char*)&lds[buf][0][0] + (iss * 256 + w * 64) * 16);
    }
#pragma unroll
    for (int iss = 0; iss < 2; ++iss) {
      int c = iss * 256 + w * 64 + lane;
      const unsigned short* gp =
          W + (size_t)(col0 + (c >> 2)) * 768 + k0 + (c & 3) * 8;
      GLD16(gp, (char*)&lds[buf][1][0] + (iss * 256 + w * 64) * 16);
    }
  };

  stage(0, 0);
  asm volatile("s_waitcnt vmcnt(0)" ::: "memory");
  __syncthreads();

  int buf = 0;
  for (int kt = 0; kt < 24; ++kt) {
    if (kt < 23) stage(buf ^ 1, (kt + 1) * 32);
    const short* Ab = &lds[buf][0][0];
    const short* Bb = &lds[buf][1][0];
    short8 a[4], b[4];
    const int koff = l4 * 8;
#pragma unroll
    for (int mt = 0; mt < 4; ++mt)
      a[mt] = *reinterpret_cast<const short8*>(
          Ab + (wr * 64 + mt * 16 + l15) * 32 + koff);
#pragma unroll
    for (int nt = 0; nt < 4; ++nt)
      b[nt] = *reinterpret_cast<const short8*>(
          Bb + (wc * 64 + nt * 16 + l15) * 32 + koff);
#pragma unroll
    for (int mt = 0; mt < 4; ++mt)
#pragma unroll
      for (int nt = 0; nt < 4; ++nt)
        acc[mt][nt] = __builtin_amdgcn_mfma_f32_16x16x32_bf16(
            a[mt], b[nt], acc[mt][nt], 0, 0, 0);
    asm volatile("s_waitcnt vmcnt(0)" ::: "memory");
    __syncthreads();
    buf ^= 1;
  }

  // epilogue: scatter into head-major layouts, bf16 cast, bias add
  const int mat = (MODE == 0) ? (col0 >= 768 ? 1 : 0) : (col0 / 768);
  const int cb = col0 - mat * 768 + wc * 64;
#pragma unroll
  for (int nt = 0; nt < 4; ++nt) {
    const int cc = cb + nt * 16 + l15;  // 0..767
    const int hh = cc >> 6, dd = cc & 63;
    float bias = 0.f;
    if (mat == 1) bias = b1[cc];
    if (MODE == 1 && mat == 2) bias = b2[cc];
#pragma unroll
    for (int mt = 0; mt < 4; ++mt) {
#pragma unroll
      for (int i = 0; i < 4; ++i) {
        const int row = row0 + wr * 64 + mt * 16 + l4 * 4 + i;  // 0..8191
        const int bb = row >> 10, nn = row & 1023;
        const int bhh = bb * 12 + hh;
        const float v = acc[mt][nt][i] + bias;
        const unsigned short bvv = f2b(v);
        if (MODE == 1 && mat == 2)
          outV[((size_t)bhh * 64 + dd) * 1024 + nn] = bvv;
        else
          outC[((size_t)bhh * 1024 + nn) * 128 + mat * 64 + dd] = bvv;
      }
    }
  }
}

// ---------------- per-key bias: kdsq[bh][m] = sum_d Kc[bh][m][0:64]^2 ------
__global__ void kdsq_kernel(const unsigned short* __restrict__ Kc,
                            float* __restrict__ kdsq) {
  int t = blockIdx.x * 256 + threadIdx.x;  // 4 lanes per row
  int r = t >> 2, part = t & 3;
  const short8* p = reinterpret_cast<const short8*>(Kc + (size_t)r * 128 + part * 16);
  float s = 0.f;
#pragma unroll
  for (int v = 0; v < 2; ++v) {
    short8 x = p[v];
#pragma unroll
    for (int j = 0; j < 8; ++j) {
      float f = b2f((unsigned short)x[j]);
      s += f * f;
    }
  }
  s += __shfl_xor(s, 1);
  s += __shfl_xor(s, 2);
  if (part == 0) kdsq[r] = s;
}

// ---------------- flash attention, head-dim 128 QK, 64 V ------------------
// scores = (Qc.Kc)/8 - kdsq/16 ; online softmax ; ctx = P.V
__global__ __launch_bounds__(256) void attn_kernel(
    const unsigned short* __restrict__ Qc, const unsigned short* __restrict__ Kc,
    const unsigned short* __restrict__ Vt, const float* __restrict__ kdsq,
    float* __restrict__ out) {
  __shared__ __align__(16) float kq[1024];
  __shared__ __align__(16) short P[4][16][72];
  const int bh = blockIdx.x >> 4;  // 0..95
  const int qb = blockIdx.x & 15;
  const int b = bh / 12, h = bh - b * 12;
  const int lane = threadIdx.x & 63;
  const int w = threadIdx.x >> 6;
  const int l15 = lane & 15, l4 = lane >> 4;

  reinterpret_cast<float4*>(kq)[threadIdx.x] =
      reinterpret_cast<const float4*>(kdsq + (size_t)bh * 1024)[threadIdx.x];
  __syncthreads();

  const int q0 = qb * 64 + w * 16;
  const unsigned short* Qbase = Qc + ((size_t)bh * 1024 + q0 + l15) * 128 + l4 * 8;
  short8 qa[4];
#pragma unroll
  for (int kk = 0; kk < 4; ++kk)
    qa[kk] = *reinterpret_cast<const short8*>(Qbase + kk * 32);

  float m_r[4], l_r[4];
  f32x4 o[4];
#pragma unroll
  for (int i = 0; i < 4; ++i) {
    m_r[i] = -1e30f;
    l_r[i] = 0.f;
  }
#pragma unroll
  for (int dt = 0; dt < 4; ++dt) o[dt] = (f32x4){0.f, 0.f, 0.f, 0.f};

  const unsigned short* Kbase = Kc + (size_t)bh * 1024 * 128;
  const unsigned short* Vbase = Vt + (size_t)bh * 64 * 1024;

  for (int kb = 0; kb < 16; ++kb) {
    float sv[4][4];  // [kc][i]
#pragma unroll
    for (int kc = 0; kc < 4; ++kc) {
      const int key = kb * 64 + kc * 16 + l15;
      f32x4 s = (f32x4){0.f, 0.f, 0.f, 0.f};
      const unsigned short* kp = Kbase + (size_t)key * 128 + l4 * 8;
#pragma unroll
      for (int kk = 0; kk < 4; ++kk) {
        short8 kf = *reinterpret_cast<const short8*>(kp + kk * 32);
        s = __builtin_amdgcn_mfma_f32_16x16x32_bf16(qa[kk], kf, s, 0, 0, 0);
      }
      const float bias = kq[key] * 0.0625f;
#pragma unroll
      for (int i = 0; i < 4; ++i) sv[kc][i] = s[i] * 0.125f - bias;
    }
    // row max over this 64-key tile (rows r = l4*4+i live in 16-lane groups)
    float mt[4];
#pragma unroll
    for (int i = 0; i < 4; ++i)
      mt[i] = fmaxf(fmaxf(sv[0][i], sv[1][i]), fmaxf(sv[2][i], sv[3][i]));
#pragma unroll
    for (int d = 1; d < 16; d <<= 1)
#pragma unroll
      for (int i = 0; i < 4; ++i) mt[i] = fmaxf(mt[i], __shfl_xor(mt[i], d));

    float corr[4], ps[4];
#pragma unroll
    for (int i = 0; i < 4; ++i) {
      const float mn = fmaxf(m_r[i], mt[i]);
      corr[i] = __expf(m_r[i] - mn);
      m_r[i] = mn;
      ps[i] = 0.f;
    }
#pragma unroll
    for (int kc = 0; kc < 4; ++kc)
#pragma unroll
      for (int i = 0; i < 4; ++i) {
        const float pv = __expf(sv[kc][i] - m_r[i]);
        sv[kc][i] = pv;
        ps[i] += pv;
      }
#pragma unroll
    for (int d = 1; d < 16; d <<= 1)
#pragma unroll
      for (int i = 0; i < 4; ++i) ps[i] += __shfl_xor(ps[i], d);
#pragma unroll
    for (int i = 0; i < 4; ++i) l_r[i] = l_r[i] * corr[i] + ps[i];
#pragma unroll
    for (int dt = 0; dt < 4; ++dt)
#pragma unroll
      for (int i = 0; i < 4; ++i) o[dt][i] *= corr[i];

    // P -> bf16 via per-wave-private LDS (no barrier needed: wave-local)
#pragma unroll
    for (int kc = 0; kc < 4; ++kc)
#pragma unroll
      for (int i = 0; i < 4; ++i)
        P[w][l4 * 4 + i][kc * 16 + l15] = (short)f2b(sv[kc][i]);

    short8 pa[2];
#pragma unroll
    for (int kk = 0; kk < 2; ++kk)
      pa[kk] = *reinterpret_cast<const short8*>(&P[w][l15][kk * 32 + l4 * 8]);
#pragma unroll
    for (int dt = 0; dt < 4; ++dt) {
      const unsigned short* vp =
          Vbase + (size_t)(dt * 16 + l15) * 1024 + kb * 64 + l4 * 8;
#pragma unroll
      for (int kk = 0; kk < 2; ++kk) {
        short8 vf = *reinterpret_cast<const short8*>(vp + kk * 32);
        o[dt] = __builtin_amdgcn_mfma_f32_16x16x32_bf16(pa[kk], vf, o[dt], 0, 0, 0);
      }
    }
  }

  float inv[4];
#pragma unroll
  for (int i = 0; i < 4; ++i) inv[i] = 1.f / l_r[i];
#pragma unroll
  for (int dt = 0; dt < 4; ++dt)
#pragma unroll
    for (int i = 0; i < 4; ++i) {
      const size_t idx =
          ((size_t)b * 1024 + q0 + l4 * 4 + i) * 768 + h * 64 + dt * 16 + l15;
      out[idx] = o[dt][i] * inv[i];
    }
}

// ---------------------------------------------------------------------------
extern "C" void kernel_launch(void* const* d_in, const int* in_sizes, int n_in,
                              void* d_out, int out_size, void* d_ws,
                              size_t ws_size, hipStream_t stream) {
  const float* query = (const float*)d_in[0];
  const float* key = (const float*)d_in[1];
  const float* Wd = (const float*)d_in[2];
  const float* Wq = (const float*)d_in[3];
  const float* bq = (const float*)d_in[4];
  const float* Wk = (const float*)d_in[5];
  const float* bk = (const float*)d_in[6];
  const float* Wv = (const float*)d_in[7];
  const float* bv = (const float*)d_in[8];
  float* out = (float*)d_out;

  char* p = (char*)d_ws;
  auto alloc = [&](size_t n) {
    char* r = p;
    p += (n + 255) & ~(size_t)255;
    return r;
  };
  unsigned short* Xq = (unsigned short*)alloc(8192ULL * 768 * 2);
  unsigned short* Xk = (unsigned short*)alloc(8192ULL * 768 * 2);
  unsigned short* Wcq = (unsigned short*)alloc(1536ULL * 768 * 2);
  unsigned short* Wck = (unsigned short*)alloc(2304ULL * 768 * 2);
  unsigned short* Qc = (unsigned short*)alloc(96ULL * 1024 * 128 * 2);
  unsigned short* Kc = (unsigned short*)alloc(96ULL * 1024 * 128 * 2);
  unsigned short* Vt = (unsigned short*)alloc(96ULL * 64 * 1024 * 2);
  float* kq = (float*)alloc(96ULL * 1024 * 4);

  cvt_kernel<<<6144, 256, 0, stream>>>(query, Xq, 1572864);
  cvt_kernel<<<6144, 256, 0, stream>>>(key, Xk, 1572864);
  cvt_kernel<<<576, 256, 0, stream>>>(Wd, Wcq, 147456);
  cvt_kernel<<<576, 256, 0, stream>>>(Wq, Wcq + 589824, 147456);
  cvt_kernel<<<576, 256, 0, stream>>>(Wd, Wck, 147456);
  cvt_kernel<<<576, 256, 0, stream>>>(Wk, Wck + 589824, 147456);
  cvt_kernel<<<576, 256, 0, stream>>>(Wv, Wck + 2 * 589824, 147456);

  proj_kernel<0><<<dim3(64, 12), 256, 0, stream>>>(Xq, Wcq, bq, nullptr, Qc, nullptr);
  proj_kernel<1><<<dim3(64, 18), 256, 0, stream>>>(Xk, Wck, bk, bv, Kc, Vt);

  kdsq_kernel<<<1536, 256, 0, stream>>>(Kc, kq);
  attn_kernel<<<1536, 256, 0, stream>>>(Qc, Kc, Vt, kq, out);
}

// Round 2
// 200.693 us; speedup vs baseline: 2.0603x; 2.0603x over previous
//
#include <hip/hip_runtime.h>
#include <stdint.h>

typedef __attribute__((ext_vector_type(8))) short short8;
typedef __attribute__((ext_vector_type(4))) short short4v;
typedef __attribute__((ext_vector_type(4))) float f32x4;

static __device__ __forceinline__ unsigned short f2b(float f) {
  unsigned int u = __builtin_bit_cast(unsigned int, f);
  u += 0x7fffu + ((u >> 16) & 1u);
  return (unsigned short)(u >> 16);
}
static __device__ __forceinline__ float b2f(unsigned short b) {
  unsigned int u = ((unsigned int)b) << 16;
  return __builtin_bit_cast(float, u);
}

#define GLD16(gp, lp)                                                          \
  __builtin_amdgcn_global_load_lds(                                            \
      (const __attribute__((address_space(1))) void*)(gp),                     \
      (__attribute__((address_space(3))) void*)(lp), 16, 0, 0)

#define MFMA16 __builtin_amdgcn_mfma_f32_16x16x32_bf16

// ---------------- fp32 -> bf16 convert (float4 -> 4x bf16) ----------------
__global__ void cvt_kernel(const float* __restrict__ src,
                           unsigned short* __restrict__ dst, int n4) {
  int i = blockIdx.x * 256 + threadIdx.x;
  if (i >= n4) return;
  float4 v = reinterpret_cast<const float4*>(src)[i];
  short4v o;
  o.x = (short)f2b(v.x);
  o.y = (short)f2b(v.y);
  o.z = (short)f2b(v.z);
  o.w = (short)f2b(v.w);
  reinterpret_cast<short4v*>(dst)[i] = o;
}

// ---------------- projection GEMM (unchanged from round 1) ----------------
template <int MODE>
__global__ __launch_bounds__(256) void proj_kernel(
    const unsigned short* __restrict__ X, const unsigned short* __restrict__ W,
    const float* __restrict__ b1, const float* __restrict__ b2,
    unsigned short* __restrict__ outC, unsigned short* __restrict__ outV) {
  __shared__ __align__(16) short lds[2][2][128 * 32];
  const int row0 = blockIdx.x * 128;
  const int col0 = blockIdx.y * 128;
  const int lane = threadIdx.x & 63;
  const int w = threadIdx.x >> 6;
  const int wr = w >> 1, wc = w & 1;
  const int l15 = lane & 15, l4 = lane >> 4;

  f32x4 acc[4][4];
#pragma unroll
  for (int i = 0; i < 4; ++i)
#pragma unroll
    for (int j = 0; j < 4; ++j) acc[i][j] = (f32x4){0.f, 0.f, 0.f, 0.f};

  auto stage = [&](int buf, int k0) {
#pragma unroll
    for (int iss = 0; iss < 2; ++iss) {
      int c = iss * 256 + w * 64 + lane;
      const unsigned short* gp =
          X + (size_t)(row0 + (c >> 2)) * 768 + k0 + (c & 3) * 8;
      GLD16(gp, (char*)&lds[buf][0][0] + (iss * 256 + w * 64) * 16);
    }
#pragma unroll
    for (int iss = 0; iss < 2; ++iss) {
      int c = iss * 256 + w * 64 + lane;
      const unsigned short* gp =
          W + (size_t)(col0 + (c >> 2)) * 768 + k0 + (c & 3) * 8;
      GLD16(gp, (char*)&lds[buf][1][0] + (iss * 256 + w * 64) * 16);
    }
  };

  stage(0, 0);
  asm volatile("s_waitcnt vmcnt(0)" ::: "memory");
  __syncthreads();

  int buf = 0;
  for (int kt = 0; kt < 24; ++kt) {
    if (kt < 23) stage(buf ^ 1, (kt + 1) * 32);
    const short* Ab = &lds[buf][0][0];
    const short* Bb = &lds[buf][1][0];
    short8 a[4], b[4];
    const int koff = l4 * 8;
#pragma unroll
    for (int mt = 0; mt < 4; ++mt)
      a[mt] = *reinterpret_cast<const short8*>(
          Ab + (wr * 64 + mt * 16 + l15) * 32 + koff);
#pragma unroll
    for (int nt = 0; nt < 4; ++nt)
      b[nt] = *reinterpret_cast<const short8*>(
          Bb + (wc * 64 + nt * 16 + l15) * 32 + koff);
#pragma unroll
    for (int mt = 0; mt < 4; ++mt)
#pragma unroll
      for (int nt = 0; nt < 4; ++nt)
        acc[mt][nt] = MFMA16(a[mt], b[nt], acc[mt][nt], 0, 0, 0);
    asm volatile("s_waitcnt vmcnt(0)" ::: "memory");
    __syncthreads();
    buf ^= 1;
  }

  const int mat = (MODE == 0) ? (col0 >= 768 ? 1 : 0) : (col0 / 768);
  const int cb = col0 - mat * 768 + wc * 64;
#pragma unroll
  for (int nt = 0; nt < 4; ++nt) {
    const int cc = cb + nt * 16 + l15;
    const int hh = cc >> 6, dd = cc & 63;
    float bias = 0.f;
    if (mat == 1) bias = b1[cc];
    if (MODE == 1 && mat == 2) bias = b2[cc];
#pragma unroll
    for (int mt = 0; mt < 4; ++mt) {
#pragma unroll
      for (int i = 0; i < 4; ++i) {
        const int row = row0 + wr * 64 + mt * 16 + l4 * 4 + i;
        const int bb = row >> 10, nn = row & 1023;
        const int bhh = bb * 12 + hh;
        const float v = acc[mt][nt][i] + bias;
        const unsigned short bvv = f2b(v);
        if (MODE == 1 && mat == 2)
          outV[((size_t)bhh * 64 + dd) * 1024 + nn] = bvv;
        else
          outC[((size_t)bhh * 1024 + nn) * 128 + mat * 64 + dd] = bvv;
      }
    }
  }
}

// ---------------- per-key bias: kdsq[bh][m] = sum_d Kc[bh][m][0:64]^2 ------
__global__ void kdsq_kernel(const unsigned short* __restrict__ Kc,
                            float* __restrict__ kdsq) {
  int t = blockIdx.x * 256 + threadIdx.x;
  int r = t >> 2, part = t & 3;
  const short8* p = reinterpret_cast<const short8*>(Kc + (size_t)r * 128 + part * 16);
  float s = 0.f;
#pragma unroll
  for (int v = 0; v < 2; ++v) {
    short8 x = p[v];
#pragma unroll
    for (int j = 0; j < 8; ++j) {
      float f = b2f((unsigned short)x[j]);
      s += f * f;
    }
  }
  s += __shfl_xor(s, 1);
  s += __shfl_xor(s, 2);
  if (part == 0) kdsq[r] = s;
}

// ---------------- flash attention: LDS-staged, double-buffered ------------
// block = 256 thr (4 waves), 128 q-rows/block (32/wave), KVBLK=64.
// K tile LDS [64][128] bf16 (16KB), V tile [64][64] (8KB), both x2 buffers,
// read-swizzled byte ^= ((row&7)<<4); staged via pre-swizzled global source.
__global__ __launch_bounds__(256, 2) void attn_kernel(
    const unsigned short* __restrict__ Qc, const unsigned short* __restrict__ Kc,
    const unsigned short* __restrict__ Vt, const float* __restrict__ kdsq,
    float* __restrict__ out) {
  __shared__ __align__(16) short kbuf[2][64 * 128];  // 32 KB
  __shared__ __align__(16) short vbuf[2][64 * 64];   // 16 KB
  __shared__ __align__(16) short P[4][16][72];       // 9 KB, per-wave
  __shared__ __align__(16) float kq[1024];           // 4 KB

  const int bh = blockIdx.x % 96;  // all 8 q-blocks of a head -> same XCD
  const int qb = blockIdx.x / 96;
  const int b = bh / 12, h = bh - b * 12;
  const int lane = threadIdx.x & 63;
  const int w = threadIdx.x >> 6;
  const int l15 = lane & 15, l4 = lane >> 4;

  const unsigned short* Kg = Kc + (size_t)bh * 1024 * 128;
  const unsigned short* Vg = Vt + (size_t)bh * 64 * 1024;

  auto stageK = [&](int bufi, int kb) {
#pragma unroll
    for (int i = 0; i < 4; ++i) {
      const int slot = i * 256 + threadIdx.x;
      const int key = slot >> 4;
      const int d0 = ((slot & 15) ^ (key & 7)) * 8;  // inverse read-swizzle
      const unsigned short* gp = Kg + (size_t)(kb * 64 + key) * 128 + d0;
      GLD16(gp, (char*)(&kbuf[bufi][0]) + (i * 256 + w * 64) * 16);
    }
  };
  auto stageV = [&](int bufi, int kb) {
#pragma unroll
    for (int i = 0; i < 2; ++i) {
      const int slot = i * 256 + threadIdx.x;
      const int row = slot >> 3;
      const int k0 = ((slot & 7) ^ (row & 7)) * 8;
      const unsigned short* gp = Vg + (size_t)row * 1024 + kb * 64 + k0;
      GLD16(gp, (char*)(&vbuf[bufi][0]) + (i * 256 + w * 64) * 16);
    }
  };

  stageK(0, 0);
  stageV(0, 0);
  reinterpret_cast<float4*>(kq)[threadIdx.x] =
      reinterpret_cast<const float4*>(kdsq + (size_t)bh * 1024)[threadIdx.x];

  // Q fragments: 32 rows per wave (2 m-tiles)
  const int q0 = qb * 128 + w * 32;
  short8 qa[2][4];
#pragma unroll
  for (int mt = 0; mt < 2; ++mt) {
    const unsigned short* Qb =
        Qc + ((size_t)bh * 1024 + q0 + mt * 16 + l15) * 128 + l4 * 8;
#pragma unroll
    for (int kk = 0; kk < 4; ++kk)
      qa[mt][kk] = *reinterpret_cast<const short8*>(Qb + kk * 32);
  }

  short8 ones;
#pragma unroll
  for (int j = 0; j < 8; ++j) ones[j] = (short)0x3F80;  // bf16 1.0

  float m_r[2][4], l_r[2][4];
  f32x4 o[2][4];
#pragma unroll
  for (int mt = 0; mt < 2; ++mt)
#pragma unroll
    for (int i = 0; i < 4; ++i) {
      m_r[mt][i] = -1e30f;
      l_r[mt][i] = 0.f;
    }
#pragma unroll
  for (int mt = 0; mt < 2; ++mt)
#pragma unroll
    for (int dt = 0; dt < 4; ++dt) o[mt][dt] = (f32x4){0.f, 0.f, 0.f, 0.f};

  const int S = (l15 & 7) << 4;
  int kof[4];
#pragma unroll
  for (int kk = 0; kk < 4; ++kk) kof[kk] = (kk * 64 + l4 * 16) ^ S;

  asm volatile("s_waitcnt vmcnt(0)" ::: "memory");
  __syncthreads();

  int buf = 0;
  for (int kb = 0; kb < 16; ++kb) {
    if (kb < 15) {
      stageK(buf ^ 1, kb + 1);
      stageV(buf ^ 1, kb + 1);
    }
    const char* kB = (const char*)(&kbuf[buf][0]) + l15 * 256;
    const char* vB = (const char*)(&vbuf[buf][0]) + l15 * 128;

    // ---- QK^T: 64 keys x 128 dims ----
    float sv[2][4][4];
#pragma unroll
    for (int kc = 0; kc < 4; ++kc) {
      const char* rb = kB + kc * 4096;
      short8 kf0 = *reinterpret_cast<const short8*>(rb + kof[0]);
      short8 kf1 = *reinterpret_cast<const short8*>(rb + kof[1]);
      short8 kf2 = *reinterpret_cast<const short8*>(rb + kof[2]);
      short8 kf3 = *reinterpret_cast<const short8*>(rb + kof[3]);
      f32x4 s0 = (f32x4){0.f, 0.f, 0.f, 0.f};
      f32x4 s1 = (f32x4){0.f, 0.f, 0.f, 0.f};
      s0 = MFMA16(qa[0][0], kf0, s0, 0, 0, 0);
      s0 = MFMA16(qa[0][1], kf1, s0, 0, 0, 0);
      s0 = MFMA16(qa[0][2], kf2, s0, 0, 0, 0);
      s0 = MFMA16(qa[0][3], kf3, s0, 0, 0, 0);
      s1 = MFMA16(qa[1][0], kf0, s1, 0, 0, 0);
      s1 = MFMA16(qa[1][1], kf1, s1, 0, 0, 0);
      s1 = MFMA16(qa[1][2], kf2, s1, 0, 0, 0);
      s1 = MFMA16(qa[1][3], kf3, s1, 0, 0, 0);
      const float bias = kq[kb * 64 + kc * 16 + l15] * 0.0625f;
#pragma unroll
      for (int i = 0; i < 4; ++i) {
        sv[0][kc][i] = s0[i] * 0.125f - bias;
        sv[1][kc][i] = s1[i] * 0.125f - bias;
      }
    }

    // ---- online softmax (defer-max, THR=8) ----
    float mx[2][4];
#pragma unroll
    for (int mt = 0; mt < 2; ++mt)
#pragma unroll
      for (int i = 0; i < 4; ++i)
        mx[mt][i] = fmaxf(fmaxf(sv[mt][0][i], sv[mt][1][i]),
                          fmaxf(sv[mt][2][i], sv[mt][3][i]));
#pragma unroll
    for (int d = 1; d < 16; d <<= 1)
#pragma unroll
      for (int mt = 0; mt < 2; ++mt)
#pragma unroll
        for (int i = 0; i < 4; ++i)
          mx[mt][i] = fmaxf(mx[mt][i], __shfl_xor(mx[mt][i], d));

    bool ok = true;
#pragma unroll
    for (int mt = 0; mt < 2; ++mt)
#pragma unroll
      for (int i = 0; i < 4; ++i) ok &= (mx[mt][i] <= m_r[mt][i] + 8.0f);
    if (!__all(ok)) {
#pragma unroll
      for (int mt = 0; mt < 2; ++mt)
#pragma unroll
        for (int i = 0; i < 4; ++i) {
          const float mn = fmaxf(m_r[mt][i], mx[mt][i]);
          const float c = __expf(m_r[mt][i] - mn);
          m_r[mt][i] = mn;
          l_r[mt][i] *= c;
#pragma unroll
          for (int dt = 0; dt < 4; ++dt) o[mt][dt][i] *= c;
        }
    }

    // ---- P = exp(sv - m) -> bf16 (trunc) via per-wave LDS; rowsum by MFMA --
    short8 pa[2][2];
#pragma unroll
    for (int mt = 0; mt < 2; ++mt) {
#pragma unroll
      for (int kc = 0; kc < 4; ++kc)
#pragma unroll
        for (int i = 0; i < 4; ++i) {
          const float p = __expf(sv[mt][kc][i] - m_r[mt][i]);
          const unsigned int u = __builtin_bit_cast(unsigned int, p);
          P[w][l4 * 4 + i][kc * 16 + l15] = (short)(u >> 16);
        }
#pragma unroll
      for (int kk = 0; kk < 2; ++kk)
        pa[mt][kk] =
            *reinterpret_cast<const short8*>(&P[w][l15][kk * 32 + l4 * 8]);
      f32x4 ls = (f32x4){0.f, 0.f, 0.f, 0.f};
      ls = MFMA16(pa[mt][0], ones, ls, 0, 0, 0);
      ls = MFMA16(pa[mt][1], ones, ls, 0, 0, 0);
#pragma unroll
      for (int i = 0; i < 4; ++i) l_r[mt][i] += ls[i];
    }

    // ---- PV ----
#pragma unroll
    for (int dt = 0; dt < 4; ++dt) {
      const char* vrb = vB + dt * 2048;
      short8 vf0 = *reinterpret_cast<const short8*>(vrb + kof[0]);
      short8 vf1 = *reinterpret_cast<const short8*>(vrb + kof[1]);
      o[0][dt] = MFMA16(pa[0][0], vf0, o[0][dt], 0, 0, 0);
      o[0][dt] = MFMA16(pa[0][1], vf1, o[0][dt], 0, 0, 0);
      o[1][dt] = MFMA16(pa[1][0], vf0, o[1][dt], 0, 0, 0);
      o[1][dt] = MFMA16(pa[1][1], vf1, o[1][dt], 0, 0, 0);
    }

    asm volatile("s_waitcnt vmcnt(0)" ::: "memory");
    __syncthreads();
    buf ^= 1;
  }

  float inv[2][4];
#pragma unroll
  for (int mt = 0; mt < 2; ++mt)
#pragma unroll
    for (int i = 0; i < 4; ++i) inv[mt][i] = 1.f / l_r[mt][i];
#pragma unroll
  for (int mt = 0; mt < 2; ++mt)
#pragma unroll
    for (int dt = 0; dt < 4; ++dt)
#pragma unroll
      for (int i = 0; i < 4; ++i) {
        const size_t idx =
            ((size_t)b * 1024 + q0 + mt * 16 + l4 * 4 + i) * 768 + h * 64 +
            dt * 16 + l15;
        out[idx] = o[mt][dt][i] * inv[mt][i];
      }
}

// ---------------------------------------------------------------------------
extern "C" void kernel_launch(void* const* d_in, const int* in_sizes, int n_in,
                              void* d_out, int out_size, void* d_ws,
                              size_t ws_size, hipStream_t stream) {
  const float* query = (const float*)d_in[0];
  const float* key = (const float*)d_in[1];
  const float* Wd = (const float*)d_in[2];
  const float* Wq = (const float*)d_in[3];
  const float* bq = (const float*)d_in[4];
  const float* Wk = (const float*)d_in[5];
  const float* bk = (const float*)d_in[6];
  const float* Wv = (const float*)d_in[7];
  const float* bv = (const float*)d_in[8];
  float* out = (float*)d_out;

  char* p = (char*)d_ws;
  auto alloc = [&](size_t n) {
    char* r = p;
    p += (n + 255) & ~(size_t)255;
    return r;
  };
  unsigned short* Xq = (unsigned short*)alloc(8192ULL * 768 * 2);
  unsigned short* Xk = (unsigned short*)alloc(8192ULL * 768 * 2);
  unsigned short* Wcq = (unsigned short*)alloc(1536ULL * 768 * 2);
  unsigned short* Wck = (unsigned short*)alloc(2304ULL * 768 * 2);
  unsigned short* Qc = (unsigned short*)alloc(96ULL * 1024 * 128 * 2);
  unsigned short* Kc = (unsigned short*)alloc(96ULL * 1024 * 128 * 2);
  unsigned short* Vt = (unsigned short*)alloc(96ULL * 64 * 1024 * 2);
  float* kq = (float*)alloc(96ULL * 1024 * 4);

  cvt_kernel<<<6144, 256, 0, stream>>>(query, Xq, 1572864);
  cvt_kernel<<<6144, 256, 0, stream>>>(key, Xk, 1572864);
  cvt_kernel<<<576, 256, 0, stream>>>(Wd, Wcq, 147456);
  cvt_kernel<<<576, 256, 0, stream>>>(Wq, Wcq + 589824, 147456);
  cvt_kernel<<<576, 256, 0, stream>>>(Wd, Wck, 147456);
  cvt_kernel<<<576, 256, 0, stream>>>(Wk, Wck + 589824, 147456);
  cvt_kernel<<<576, 256, 0, stream>>>(Wv, Wck + 2 * 589824, 147456);

  proj_kernel<0><<<dim3(64, 12), 256, 0, stream>>>(Xq, Wcq, bq, nullptr, Qc, nullptr);
  proj_kernel<1><<<dim3(64, 18), 256, 0, stream>>>(Xk, Wck, bk, bv, Kc, Vt);

  kdsq_kernel<<<1536, 256, 0, stream>>>(Kc, kq);
  attn_kernel<<<768, 256, 0, stream>>>(Qc, Kc, Vt, kq, out);
}

// Round 3
// 176.840 us; speedup vs baseline: 2.3383x; 1.1349x over previous
//
#include <hip/hip_runtime.h>
#include <stdint.h>

typedef __attribute__((ext_vector_type(8))) short short8;
typedef __attribute__((ext_vector_type(4))) short short4v;
typedef __attribute__((ext_vector_type(4))) float f32x4;
typedef __attribute__((ext_vector_type(16))) float f32x16;
typedef __attribute__((ext_vector_type(4))) int int4v;

static __device__ __forceinline__ unsigned short f2b(float f) {
  unsigned int u = __builtin_bit_cast(unsigned int, f);
  u += 0x7fffu + ((u >> 16) & 1u);
  return (unsigned short)(u >> 16);
}
static __device__ __forceinline__ float b2f(unsigned short b) {
  unsigned int u = ((unsigned int)b) << 16;
  return __builtin_bit_cast(float, u);
}

#define GLD16(gp, lp)                                                          \
  __builtin_amdgcn_global_load_lds(                                            \
      (const __attribute__((address_space(1))) void*)(gp),                     \
      (__attribute__((address_space(3))) void*)(lp), 16, 0, 0)

#define MFMA16 __builtin_amdgcn_mfma_f32_16x16x32_bf16
#define MFMA32 __builtin_amdgcn_mfma_f32_32x32x16_bf16

#define CVTPK(dst, lo, hi)                                                     \
  asm("v_cvt_pk_bf16_f32 %0, %1, %2" : "=v"(dst) : "v"(lo), "v"(hi))
#define PLSWAP(x, y)                                                           \
  asm volatile("v_permlane32_swap_b32 %0, %1" : "+v"(x), "+v"(y))

// QSC = 0.125 * log2(e); C2 = 0.0625 * log2(e)
#define QSC 0.18033688011112113f
#define C2 0.09016844005556057f

// ---------------- fp32 -> bf16 convert (float4 -> 4x bf16) ----------------
__global__ void cvt_kernel(const float* __restrict__ src,
                           unsigned short* __restrict__ dst, int n4) {
  int i = blockIdx.x * 256 + threadIdx.x;
  if (i >= n4) return;
  float4 v = reinterpret_cast<const float4*>(src)[i];
  short4v o;
  o.x = (short)f2b(v.x);
  o.y = (short)f2b(v.y);
  o.z = (short)f2b(v.z);
  o.w = (short)f2b(v.w);
  reinterpret_cast<short4v*>(dst)[i] = o;
}

// ---------------- projection GEMM ----------------
// MODE 0 (query): NC=1536, {0: qd, 1: q+bq} -> Qc[..][128], both scaled by QSC
// MODE 1 (key):   NC=2304, {0: kd, 1: k+bk} -> Kc, {2: v+bv} -> Vt
template <int MODE>
__global__ __launch_bounds__(256) void proj_kernel(
    const unsigned short* __restrict__ X, const unsigned short* __restrict__ W,
    const float* __restrict__ b1, const float* __restrict__ b2,
    unsigned short* __restrict__ outC, unsigned short* __restrict__ outV) {
  __shared__ __align__(16) short lds[2][2][128 * 32];
  const int row0 = blockIdx.x * 128;
  const int col0 = blockIdx.y * 128;
  const int lane = threadIdx.x & 63;
  const int w = threadIdx.x >> 6;
  const int wr = w >> 1, wc = w & 1;
  const int l15 = lane & 15, l4 = lane >> 4;

  f32x4 acc[4][4];
#pragma unroll
  for (int i = 0; i < 4; ++i)
#pragma unroll
    for (int j = 0; j < 4; ++j) acc[i][j] = (f32x4){0.f, 0.f, 0.f, 0.f};

  auto stage = [&](int buf, int k0) {
#pragma unroll
    for (int iss = 0; iss < 2; ++iss) {
      int c = iss * 256 + w * 64 + lane;
      const unsigned short* gp =
          X + (size_t)(row0 + (c >> 2)) * 768 + k0 + (c & 3) * 8;
      GLD16(gp, (char*)&lds[buf][0][0] + (iss * 256 + w * 64) * 16);
    }
#pragma unroll
    for (int iss = 0; iss < 2; ++iss) {
      int c = iss * 256 + w * 64 + lane;
      const unsigned short* gp =
          W + (size_t)(col0 + (c >> 2)) * 768 + k0 + (c & 3) * 8;
      GLD16(gp, (char*)&lds[buf][1][0] + (iss * 256 + w * 64) * 16);
    }
  };

  stage(0, 0);
  asm volatile("s_waitcnt vmcnt(0)" ::: "memory");
  __syncthreads();

  int buf = 0;
  for (int kt = 0; kt < 24; ++kt) {
    if (kt < 23) stage(buf ^ 1, (kt + 1) * 32);
    const short* Ab = &lds[buf][0][0];
    const short* Bb = &lds[buf][1][0];
    short8 a[4], b[4];
    const int koff = l4 * 8;
#pragma unroll
    for (int mt = 0; mt < 4; ++mt)
      a[mt] = *reinterpret_cast<const short8*>(
          Ab + (wr * 64 + mt * 16 + l15) * 32 + koff);
#pragma unroll
    for (int nt = 0; nt < 4; ++nt)
      b[nt] = *reinterpret_cast<const short8*>(
          Bb + (wc * 64 + nt * 16 + l15) * 32 + koff);
#pragma unroll
    for (int mt = 0; mt < 4; ++mt)
#pragma unroll
      for (int nt = 0; nt < 4; ++nt)
        acc[mt][nt] = MFMA16(a[mt], b[nt], acc[mt][nt], 0, 0, 0);
    asm volatile("s_waitcnt vmcnt(0)" ::: "memory");
    __syncthreads();
    buf ^= 1;
  }

  const int mat = (MODE == 0) ? (col0 >= 768 ? 1 : 0) : (col0 / 768);
  const int cb = col0 - mat * 768 + wc * 64;
#pragma unroll
  for (int nt = 0; nt < 4; ++nt) {
    const int cc = cb + nt * 16 + l15;
    const int hh = cc >> 6, dd = cc & 63;
    float bias = 0.f;
    if (mat == 1) bias = b1[cc];
    if (MODE == 1 && mat == 2) bias = b2[cc];
#pragma unroll
    for (int mt = 0; mt < 4; ++mt) {
#pragma unroll
      for (int i = 0; i < 4; ++i) {
        const int row = row0 + wr * 64 + mt * 16 + l4 * 4 + i;
        const int bb = row >> 10, nn = row & 1023;
        const int bhh = bb * 12 + hh;
        float v = acc[mt][nt][i] + bias;
        if (MODE == 0) v *= QSC;  // fold 0.125*log2e into Q
        const unsigned short bvv = f2b(v);
        if (MODE == 1 && mat == 2)
          outV[((size_t)bhh * 64 + dd) * 1024 + nn] = bvv;
        else
          outC[((size_t)bhh * 1024 + nn) * 128 + mat * 64 + dd] = bvv;
      }
    }
  }
}

// ---------------- w[k] = exp2(-|kd|^2 * C2), bf16 -------------------------
__global__ void wq_kernel(const unsigned short* __restrict__ Kc,
                          unsigned short* __restrict__ wq) {
  int t = blockIdx.x * 256 + threadIdx.x;
  int r = t >> 2, part = t & 3;
  const short8* p =
      reinterpret_cast<const short8*>(Kc + (size_t)r * 128 + part * 16);
  float s = 0.f;
#pragma unroll
  for (int v = 0; v < 2; ++v) {
    short8 x = p[v];
#pragma unroll
    for (int j = 0; j < 8; ++j) {
      float f = b2f((unsigned short)x[j]);
      s += f * f;
    }
  }
  s += __shfl_xor(s, 1);
  s += __shfl_xor(s, 2);
  if (part == 0) wq[r] = f2b(__builtin_amdgcn_exp2f(-s * C2));
}

// ---------------- Vt *= w[k] (per key column) ----------------------------
__global__ __launch_bounds__(256) void vscale_kernel(
    const unsigned short* __restrict__ wq, unsigned short* __restrict__ Vt) {
  __shared__ float wf[1024];
  const int bh = blockIdx.x;
  const int t = threadIdx.x;
#pragma unroll
  for (int i = 0; i < 4; ++i)
    wf[i * 256 + t] = b2f(wq[(size_t)bh * 1024 + i * 256 + t]);
  __syncthreads();
  unsigned short* Vb = Vt + (size_t)bh * 64 * 1024;
#pragma unroll
  for (int i = 0; i < 32; ++i) {
    const int idx = i * 256 + t;
    const int e0 = idx * 8;
    const int k0 = e0 & 1023;
    short8 v = *reinterpret_cast<const short8*>(Vb + e0);
#pragma unroll
    for (int j = 0; j < 8; ++j)
      v[j] = (short)f2b(b2f((unsigned short)v[j]) * wf[k0 + j]);
    *reinterpret_cast<short8*>(Vb + e0) = v;
  }
}

// ---------------- flash attention: swapped-QK 32x32, in-register softmax --
// block = 256 thr (4 waves), 128 q/block (32/wave), KVBLK=64, 3 blocks/CU.
__global__ __launch_bounds__(256, 3) void attn_kernel(
    const unsigned short* __restrict__ Qc, const unsigned short* __restrict__ Kc,
    const unsigned short* __restrict__ Vt, const unsigned short* __restrict__ wq,
    float* __restrict__ out) {
  __shared__ __align__(16) short kbuf[2][64 * 128];  // 32 KB, swz (row&15)<<4
  __shared__ __align__(16) short vbuf[2][64 * 64];   // 16 KB, swz (row&7)<<4
  __shared__ __align__(16) short wbuf[1024];         // 2 KB

  const int bh = blockIdx.x % 96;
  const int qb = blockIdx.x / 96;
  const int b = bh / 12, h = bh - b * 12;
  const int lane = threadIdx.x & 63;
  const int w = threadIdx.x >> 6;
  const int l31 = lane & 31, l5 = lane >> 5;

  const unsigned short* Kg = Kc + (size_t)bh * 1024 * 128;
  const unsigned short* Vg = Vt + (size_t)bh * 64 * 1024;

  auto stageK = [&](int bufi, int kb) {
#pragma unroll
    for (int i = 0; i < 4; ++i) {
      const int slot = i * 256 + threadIdx.x;
      const int row = slot >> 4;
      const int d0 = ((slot & 15) ^ (row & 15)) * 8;
      const unsigned short* gp = Kg + (size_t)(kb * 64 + row) * 128 + d0;
      GLD16(gp, (char*)(&kbuf[bufi][0]) + (i * 256 + w * 64) * 16);
    }
  };
  auto stageV = [&](int bufi, int kb) {
#pragma unroll
    for (int i = 0; i < 2; ++i) {
      const int slot = i * 256 + threadIdx.x;
      const int row = slot >> 3;
      const int k0 = ((slot & 7) ^ (row & 7)) * 8;
      const unsigned short* gp = Vg + (size_t)row * 1024 + kb * 64 + k0;
      GLD16(gp, (char*)(&vbuf[bufi][0]) + (i * 256 + w * 64) * 16);
    }
  };

  stageK(0, 0);
  stageV(0, 0);
  if (w < 2) {
    const unsigned short* gp = wq + (size_t)bh * 1024 + (w * 64 + lane) * 8;
    GLD16(gp, (char*)(&wbuf[0]) + w * 1024);
  }

  // Q fragments (B-operand): lane l holds Q[q=l31][k=l5*8+j], 8 k-steps
  const unsigned short* Qb =
      Qc + ((size_t)bh * 1024 + qb * 128 + w * 32 + l31) * 128 + l5 * 8;
  short8 qf[8];
#pragma unroll
  for (int s = 0; s < 8; ++s)
    qf[s] = *reinterpret_cast<const short8*>(Qb + s * 16);

  f32x16 o0, o1, la;
#pragma unroll
  for (int r = 0; r < 16; ++r) {
    o0[r] = 0.f;
    o1[r] = 0.f;
    la[r] = 0.f;
  }
  float m = -1e30f;

  const int S4 = (lane & 15) << 4;
  const int S3 = (lane & 7) << 4;
  const int ko = l5 * 16;

  asm volatile("s_waitcnt vmcnt(0)" ::: "memory");
  __syncthreads();

  int buf = 0;
  for (int kb = 0; kb < 16; ++kb) {
    if (kb < 15) {
      stageK(buf ^ 1, kb + 1);
      stageV(buf ^ 1, kb + 1);
    }

    // ---- S^T = K . Q^T : rows=keys, cols=q (lane owns q=l31) ----
    const char* kB = (const char*)(&kbuf[buf][0]) + l31 * 256;
    f32x16 s0, s1;
#pragma unroll
    for (int r = 0; r < 16; ++r) {
      s0[r] = 0.f;
      s1[r] = 0.f;
    }
#pragma unroll
    for (int s = 0; s < 8; ++s) {
      const int off = (s * 32 + ko) ^ S4;
      short8 a0 = *reinterpret_cast<const short8*>(kB + off);
      short8 a1 = *reinterpret_cast<const short8*>(kB + 8192 + off);
      s0 = MFMA32(a0, qf[s], s0, 0, 0, 0);
      s1 = MFMA32(a1, qf[s], s1, 0, 0, 0);
    }

    // ---- tile max (in-register + one cross-half swap) ----
    float mx = s0[0];
#pragma unroll
    for (int r = 1; r < 16; ++r) mx = fmaxf(mx, s0[r]);
#pragma unroll
    for (int r = 0; r < 16; ++r) mx = fmaxf(mx, s1[r]);
    mx = fmaxf(mx, __shfl_xor(mx, 32));

    // ---- defer-max rescale (THR = 11 in log2 domain) ----
    if (!__all(mx <= m + 11.0f)) {
      const float mn = fmaxf(m, mx);
      const float c = __builtin_amdgcn_exp2f(m - mn);
      m = mn;
      float cr[16];
#pragma unroll
      for (int r = 0; r < 16; ++r)
        cr[r] = __shfl(c, (r & 3) + 8 * (r >> 2) + 4 * l5);
#pragma unroll
      for (int r = 0; r < 16; ++r) {
        la[r] *= cr[r];
        o0[r] *= cr[r];
        o1[r] *= cr[r];
      }
    }

    // ---- P = exp2(S - m), cvt to bf16 in-register ----
#pragma unroll
    for (int r = 0; r < 16; ++r) {
      s0[r] = __builtin_amdgcn_exp2f(s0[r] - m);
      s1[r] = __builtin_amdgcn_exp2f(s1[r] - m);
    }
    unsigned int u[16];
#pragma unroll
    for (int j = 0; j < 8; ++j) {
      CVTPK(u[j], s0[2 * j], s0[2 * j + 1]);
      CVTPK(u[8 + j], s1[2 * j], s1[2 * j + 1]);
    }
    PLSWAP(u[0], u[2]);
    PLSWAP(u[1], u[3]);
    PLSWAP(u[4], u[6]);
    PLSWAP(u[5], u[7]);
    PLSWAP(u[8], u[10]);
    PLSWAP(u[9], u[11]);
    PLSWAP(u[12], u[14]);
    PLSWAP(u[13], u[15]);
    short8 pa[4];
    {
      int4v t0 = {(int)u[0], (int)u[1], (int)u[2], (int)u[3]};
      int4v t1 = {(int)u[4], (int)u[5], (int)u[6], (int)u[7]};
      int4v t2 = {(int)u[8], (int)u[9], (int)u[10], (int)u[11]};
      int4v t3 = {(int)u[12], (int)u[13], (int)u[14], (int)u[15]};
      pa[0] = __builtin_bit_cast(short8, t0);
      pa[1] = __builtin_bit_cast(short8, t1);
      pa[2] = __builtin_bit_cast(short8, t2);
      pa[3] = __builtin_bit_cast(short8, t3);
    }

    // ---- PV (V pre-scaled by w) + rowsum via w-MFMA ----
    const char* vB = (const char*)(&vbuf[buf][0]) + l31 * 128;
    const char* wB = (const char*)(&wbuf[0]) + kb * 128 + ko;
#pragma unroll
    for (int kk = 0; kk < 4; ++kk) {
      const int off = (kk * 32 + ko) ^ S3;
      short8 v0 = *reinterpret_cast<const short8*>(vB + off);
      short8 v1 = *reinterpret_cast<const short8*>(vB + 4096 + off);
      short8 wf = *reinterpret_cast<const short8*>(wB + kk * 32);
      o0 = MFMA32(pa[kk], v0, o0, 0, 0, 0);
      o1 = MFMA32(pa[kk], v1, o1, 0, 0, 0);
      la = MFMA32(pa[kk], wf, la, 0, 0, 0);
    }

    asm volatile("s_waitcnt vmcnt(0)" ::: "memory");
    __syncthreads();
    buf ^= 1;
  }

  // ---- epilogue: out[q][d] = O[q][d] / l[q] ----
  const int qbase = b * 1024 + qb * 128 + w * 32;
#pragma unroll
  for (int r = 0; r < 16; ++r) {
    const float iv = __builtin_amdgcn_rcpf(la[r]);
    const int q = qbase + (r & 3) + 8 * (r >> 2) + 4 * l5;
    float* op = out + (size_t)q * 768 + h * 64 + l31;
    op[0] = o0[r] * iv;
    op[32] = o1[r] * iv;
  }
}

// ---------------------------------------------------------------------------
extern "C" void kernel_launch(void* const* d_in, const int* in_sizes, int n_in,
                              void* d_out, int out_size, void* d_ws,
                              size_t ws_size, hipStream_t stream) {
  const float* query = (const float*)d_in[0];
  const float* key = (const float*)d_in[1];
  const float* Wd = (const float*)d_in[2];
  const float* Wq = (const float*)d_in[3];
  const float* bq = (const float*)d_in[4];
  const float* Wk = (const float*)d_in[5];
  const float* bk = (const float*)d_in[6];
  const float* Wv = (const float*)d_in[7];
  const float* bv = (const float*)d_in[8];
  float* out = (float*)d_out;

  char* p = (char*)d_ws;
  auto alloc = [&](size_t n) {
    char* r = p;
    p += (n + 255) & ~(size_t)255;
    return r;
  };
  unsigned short* Xq = (unsigned short*)alloc(8192ULL * 768 * 2);
  unsigned short* Xk = (unsigned short*)alloc(8192ULL * 768 * 2);
  unsigned short* Wcq = (unsigned short*)alloc(1536ULL * 768 * 2);
  unsigned short* Wck = (unsigned short*)alloc(2304ULL * 768 * 2);
  unsigned short* Qc = (unsigned short*)alloc(96ULL * 1024 * 128 * 2);
  unsigned short* Kc = (unsigned short*)alloc(96ULL * 1024 * 128 * 2);
  unsigned short* Vt = (unsigned short*)alloc(96ULL * 64 * 1024 * 2);
  unsigned short* wqv = (unsigned short*)alloc(96ULL * 1024 * 2);

  cvt_kernel<<<6144, 256, 0, stream>>>(query, Xq, 1572864);
  cvt_kernel<<<6144, 256, 0, stream>>>(key, Xk, 1572864);
  cvt_kernel<<<576, 256, 0, stream>>>(Wd, Wcq, 147456);
  cvt_kernel<<<576, 256, 0, stream>>>(Wq, Wcq + 589824, 147456);
  cvt_kernel<<<576, 256, 0, stream>>>(Wd, Wck, 147456);
  cvt_kernel<<<576, 256, 0, stream>>>(Wk, Wck + 589824, 147456);
  cvt_kernel<<<576, 256, 0, stream>>>(Wv, Wck + 2 * 589824, 147456);

  proj_kernel<0><<<dim3(64, 12), 256, 0, stream>>>(Xq, Wcq, bq, nullptr, Qc, nullptr);
  proj_kernel<1><<<dim3(64, 18), 256, 0, stream>>>(Xk, Wck, bk, bv, Kc, Vt);

  wq_kernel<<<1536, 256, 0, stream>>>(Kc, wqv);
  vscale_kernel<<<96, 256, 0, stream>>>(wqv, Vt);

  attn_kernel<<<768, 256, 0, stream>>>(Qc, Kc, Vt, wqv, out);
}

// Round 5
// 171.062 us; speedup vs baseline: 2.4172x; 1.0338x over previous
//
#include <hip/hip_runtime.h>
#include <stdint.h>

typedef __attribute__((ext_vector_type(8))) short short8;
typedef __attribute__((ext_vector_type(4))) short short4v;
typedef __attribute__((ext_vector_type(4))) float f32x4;
typedef __attribute__((ext_vector_type(16))) float f32x16;
typedef __attribute__((ext_vector_type(4))) int int4v;

static __device__ __forceinline__ unsigned short f2b(float f) {
  unsigned int u = __builtin_bit_cast(unsigned int, f);
  u += 0x7fffu + ((u >> 16) & 1u);
  return (unsigned short)(u >> 16);
}
static __device__ __forceinline__ float b2f(unsigned short b) {
  unsigned int u = ((unsigned int)b) << 16;
  return __builtin_bit_cast(float, u);
}

#define GLD16(gp, lp)                                                          \
  __builtin_amdgcn_global_load_lds(                                            \
      (const __attribute__((address_space(1))) void*)(gp),                     \
      (__attribute__((address_space(3))) void*)(lp), 16, 0, 0)

#define MFMA16 __builtin_amdgcn_mfma_f32_16x16x32_bf16
#define MFMA32 __builtin_amdgcn_mfma_f32_32x32x16_bf16

#define CVTPK(dst, lo, hi)                                                     \
  asm("v_cvt_pk_bf16_f32 %0, %1, %2" : "=v"(dst) : "v"(lo), "v"(hi))
#define PLSWAP(x, y)                                                           \
  asm volatile("v_permlane32_swap_b32 %0, %1" : "+v"(x), "+v"(y))

// QSC = 0.125 * log2(e); C2 = 0.0625 * log2(e)
#define QSC 0.18033688011112113f
#define C2 0.09016844005556057f

// ---------------- fp32 -> bf16 converts (fused launches) ------------------
__global__ void cvtx_kernel(const float* __restrict__ q,
                            const float* __restrict__ k,
                            unsigned short* __restrict__ Xq,
                            unsigned short* __restrict__ Xk) {
  const int bx = blockIdx.x;
  const bool lo = bx < 6144;
  const float* src = lo ? q : k;
  unsigned short* dst = lo ? Xq : Xk;
  const int i = (lo ? bx : bx - 6144) * 256 + threadIdx.x;
  float4 v = reinterpret_cast<const float4*>(src)[i];
  short4v o;
  o.x = (short)f2b(v.x);
  o.y = (short)f2b(v.y);
  o.z = (short)f2b(v.z);
  o.w = (short)f2b(v.w);
  reinterpret_cast<short4v*>(dst)[i] = o;
}

__global__ void cvtw_kernel(const float* __restrict__ Wd,
                            const float* __restrict__ Wq,
                            const float* __restrict__ Wk,
                            const float* __restrict__ Wv,
                            unsigned short* __restrict__ Wcq,
                            unsigned short* __restrict__ Wck) {
  const int bx = blockIdx.x;
  const int seg = bx / 576;
  const int i = (bx - seg * 576) * 256 + threadIdx.x;
  const float* src;
  unsigned short* dst;
  switch (seg) {
    case 0: src = Wd; dst = Wcq; break;
    case 1: src = Wq; dst = Wcq + 589824; break;
    case 2: src = Wd; dst = Wck; break;
    case 3: src = Wk; dst = Wck + 589824; break;
    default: src = Wv; dst = Wck + 1179648; break;
  }
  float4 v = reinterpret_cast<const float4*>(src)[i];
  short4v o;
  o.x = (short)f2b(v.x);
  o.y = (short)f2b(v.y);
  o.z = (short)f2b(v.z);
  o.w = (short)f2b(v.w);
  reinterpret_cast<short4v*>(dst)[i] = o;
}

// ---------------- fused projection GEMM (both inputs, one dispatch) -------
// grid (64, 30): by<12 -> query path (Xq x Wcq), else key path (Xk x Wck).
// LDS tiles swizzled at 16B-slot granularity (slot ^= row&3) via
// pre-swizzled global source (global_load_lds writes linearly).
// Epilogue: round-3 direct scalar scatter (replay-proven).
__global__ __launch_bounds__(256) void proj_kernel(
    const unsigned short* __restrict__ Xq, const unsigned short* __restrict__ Xk,
    const unsigned short* __restrict__ Wcq, const unsigned short* __restrict__ Wck,
    const float* __restrict__ bq, const float* __restrict__ bk,
    const float* __restrict__ bv, unsigned short* __restrict__ Qc,
    unsigned short* __restrict__ Kc, unsigned short* __restrict__ Vt) {
  __shared__ __align__(16) short lds[2][2][128 * 32];
  const int by = blockIdx.y;
  const bool mode0 = (by < 12);
  const unsigned short* X = mode0 ? Xq : Xk;
  const unsigned short* W = mode0 ? Wcq : Wck;
  const int col0 = (mode0 ? by : by - 12) * 128;
  const int row0 = blockIdx.x * 128;
  const int lane = threadIdx.x & 63;
  const int w = threadIdx.x >> 6;
  const int wr = w >> 1, wc = w & 1;
  const int l15 = lane & 15, l4 = lane >> 4;

  f32x4 acc[4][4];
#pragma unroll
  for (int i = 0; i < 4; ++i)
#pragma unroll
    for (int j = 0; j < 4; ++j) acc[i][j] = (f32x4){0.f, 0.f, 0.f, 0.f};

  auto stage = [&](int buf, int k0) {
#pragma unroll
    for (int iss = 0; iss < 2; ++iss) {
      const int c = iss * 256 + w * 64 + lane;
      const int r = c >> 2;
      const int sl = (c & 3) ^ (r & 3);
      const unsigned short* gp = X + (size_t)(row0 + r) * 768 + k0 + sl * 8;
      GLD16(gp, (char*)&lds[buf][0][0] + (iss * 256 + w * 64) * 16);
    }
#pragma unroll
    for (int iss = 0; iss < 2; ++iss) {
      const int c = iss * 256 + w * 64 + lane;
      const int r = c >> 2;
      const int sl = (c & 3) ^ (r & 3);
      const unsigned short* gp = W + (size_t)(col0 + r) * 768 + k0 + sl * 8;
      GLD16(gp, (char*)&lds[buf][1][0] + (iss * 256 + w * 64) * 16);
    }
  };

  stage(0, 0);
  asm volatile("s_waitcnt vmcnt(0)" ::: "memory");
  __syncthreads();

  int buf = 0;
  for (int kt = 0; kt < 24; ++kt) {
    if (kt < 23) stage(buf ^ 1, (kt + 1) * 32);
    const char* Ab = (const char*)&lds[buf][0][0];
    const char* Bb = (const char*)&lds[buf][1][0];
    short8 a[4], b[4];
#pragma unroll
    for (int mt = 0; mt < 4; ++mt) {
      const int r = wr * 64 + mt * 16 + l15;
      a[mt] = *reinterpret_cast<const short8*>(Ab + r * 64 +
                                               ((l4 ^ (r & 3)) << 4));
    }
#pragma unroll
    for (int nt = 0; nt < 4; ++nt) {
      const int r = wc * 64 + nt * 16 + l15;
      b[nt] = *reinterpret_cast<const short8*>(Bb + r * 64 +
                                               ((l4 ^ (r & 3)) << 4));
    }
#pragma unroll
    for (int mt = 0; mt < 4; ++mt)
#pragma unroll
      for (int nt = 0; nt < 4; ++nt)
        acc[mt][nt] = MFMA16(a[mt], b[nt], acc[mt][nt], 0, 0, 0);
    asm volatile("s_waitcnt vmcnt(0)" ::: "memory");
    __syncthreads();
    buf ^= 1;
  }

  // ---- epilogue: round-3 style direct scatter (replay-proven) ----
  const int mat = mode0 ? (col0 >= 768 ? 1 : 0) : (col0 / 768);
  const int cb = col0 - mat * 768 + wc * 64;
  const float scale = mode0 ? QSC : 1.0f;
  const float* barr = mode0 ? bq : (mat == 2 ? bv : bk);
  unsigned short* outC = mode0 ? Qc : Kc;
#pragma unroll
  for (int nt = 0; nt < 4; ++nt) {
    const int cc = cb + nt * 16 + l15;  // 0..767
    const int hh = cc >> 6, dd = cc & 63;
    const float bias = (mat >= 1) ? barr[cc] : 0.f;
#pragma unroll
    for (int mt = 0; mt < 4; ++mt) {
#pragma unroll
      for (int i = 0; i < 4; ++i) {
        const int row = row0 + wr * 64 + mt * 16 + l4 * 4 + i;
        const int bb = row >> 10, nn = row & 1023;
        const int bhh = bb * 12 + hh;
        const float v = (acc[mt][nt][i] + bias) * scale;
        const unsigned short bvv = f2b(v);
        if (!mode0 && mat == 2)
          Vt[((size_t)bhh * 64 + dd) * 1024 + nn] = bvv;
        else
          outC[((size_t)bhh * 1024 + nn) * 128 + mat * 64 + dd] = bvv;
      }
    }
  }
}

// ---------------- w = exp2(-|kd|^2*C2); Vs = Vt * w (no RMW) --------------
__global__ __launch_bounds__(256) void wv_kernel(
    const unsigned short* __restrict__ Kc, unsigned short* __restrict__ wq,
    const unsigned short* __restrict__ Vt, unsigned short* __restrict__ Vs) {
  __shared__ float wf[1024];
  const int bh = blockIdx.x;
  const int t = threadIdx.x;
  const int part = t & 3;
  const unsigned short* Kb = Kc + (size_t)bh * 1024 * 128;
#pragma unroll
  for (int it = 0; it < 16; ++it) {
    const int key = it * 64 + (t >> 2);
    const short8* p =
        reinterpret_cast<const short8*>(Kb + (size_t)key * 128 + part * 16);
    float s = 0.f;
    short8 x0 = p[0], x1 = p[1];
#pragma unroll
    for (int j = 0; j < 8; ++j) {
      const float f0 = b2f((unsigned short)x0[j]);
      const float f1 = b2f((unsigned short)x1[j]);
      s += f0 * f0 + f1 * f1;
    }
    s += __shfl_xor(s, 1);
    s += __shfl_xor(s, 2);
    if (part == 0) {
      const unsigned short wb = f2b(__builtin_amdgcn_exp2f(-s * C2));
      wf[key] = b2f(wb);  // bf16-rounded: consistent num/denominator
      wq[(size_t)bh * 1024 + key] = wb;
    }
  }
  __syncthreads();
  const unsigned short* Vb = Vt + (size_t)bh * 64 * 1024;
  unsigned short* Ob = Vs + (size_t)bh * 64 * 1024;
#pragma unroll
  for (int i = 0; i < 32; ++i) {
    const int e0 = (i * 256 + t) * 8;
    const int k0 = e0 & 1023;
    short8 v = *reinterpret_cast<const short8*>(Vb + e0);
#pragma unroll
    for (int j = 0; j < 8; ++j)
      v[j] = (short)f2b(b2f((unsigned short)v[j]) * wf[k0 + j]);
    *reinterpret_cast<short8*>(Ob + e0) = v;
  }
}

// ---------------- flash attention: swapped-QK 32x32, in-register softmax --
__global__ __launch_bounds__(256, 3) void attn_kernel(
    const unsigned short* __restrict__ Qc, const unsigned short* __restrict__ Kc,
    const unsigned short* __restrict__ Vs, const unsigned short* __restrict__ wq,
    float* __restrict__ out) {
  __shared__ __align__(16) short kbuf[2][64 * 128];  // 32 KB, swz (row&15)<<4
  __shared__ __align__(16) short vbuf[2][64 * 64];   // 16 KB, swz (row&7)<<4
  __shared__ __align__(16) short wbuf[1024];         // 2 KB

  const int bh = blockIdx.x % 96;
  const int qb = blockIdx.x / 96;
  const int b = bh / 12, h = bh - b * 12;
  const int lane = threadIdx.x & 63;
  const int w = threadIdx.x >> 6;
  const int l31 = lane & 31, l5 = lane >> 5;

  const unsigned short* Kg = Kc + (size_t)bh * 1024 * 128;
  const unsigned short* Vg = Vs + (size_t)bh * 64 * 1024;

  auto stageK = [&](int bufi, int kb) {
#pragma unroll
    for (int i = 0; i < 4; ++i) {
      const int slot = i * 256 + threadIdx.x;
      const int row = slot >> 4;
      const int d0 = ((slot & 15) ^ (row & 15)) * 8;
      const unsigned short* gp = Kg + (size_t)(kb * 64 + row) * 128 + d0;
      GLD16(gp, (char*)(&kbuf[bufi][0]) + (i * 256 + w * 64) * 16);
    }
  };
  auto stageV = [&](int bufi, int kb) {
#pragma unroll
    for (int i = 0; i < 2; ++i) {
      const int slot = i * 256 + threadIdx.x;
      const int row = slot >> 3;
      const int k0 = ((slot & 7) ^ (row & 7)) * 8;
      const unsigned short* gp = Vg + (size_t)row * 1024 + kb * 64 + k0;
      GLD16(gp, (char*)(&vbuf[bufi][0]) + (i * 256 + w * 64) * 16);
    }
  };

  stageK(0, 0);
  stageV(0, 0);
  if (w < 2) {
    const unsigned short* gp = wq + (size_t)bh * 1024 + (w * 64 + lane) * 8;
    GLD16(gp, (char*)(&wbuf[0]) + w * 1024);
  }

  const unsigned short* Qb =
      Qc + ((size_t)bh * 1024 + qb * 128 + w * 32 + l31) * 128 + l5 * 8;
  short8 qf[8];
#pragma unroll
  for (int s = 0; s < 8; ++s)
    qf[s] = *reinterpret_cast<const short8*>(Qb + s * 16);

  f32x16 o0, o1, la;
#pragma unroll
  for (int r = 0; r < 16; ++r) {
    o0[r] = 0.f;
    o1[r] = 0.f;
    la[r] = 0.f;
  }
  float m = -1e30f;

  const int S4 = (lane & 15) << 4;
  const int S3 = (lane & 7) << 4;
  const int ko = l5 * 16;

  asm volatile("s_waitcnt vmcnt(0)" ::: "memory");
  __syncthreads();

  int buf = 0;
  for (int kb = 0; kb < 16; ++kb) {
    if (kb < 15) {
      stageK(buf ^ 1, kb + 1);
      stageV(buf ^ 1, kb + 1);
    }

    const char* kB = (const char*)(&kbuf[buf][0]) + l31 * 256;
    f32x16 s0, s1;
#pragma unroll
    for (int r = 0; r < 16; ++r) {
      s0[r] = 0.f;
      s1[r] = 0.f;
    }
#pragma unroll
    for (int s = 0; s < 8; ++s) {
      const int off = (s * 32 + ko) ^ S4;
      short8 a0 = *reinterpret_cast<const short8*>(kB + off);
      short8 a1 = *reinterpret_cast<const short8*>(kB + 8192 + off);
      s0 = MFMA32(a0, qf[s], s0, 0, 0, 0);
      s1 = MFMA32(a1, qf[s], s1, 0, 0, 0);
    }

    float mx = s0[0];
#pragma unroll
    for (int r = 1; r < 16; ++r) mx = fmaxf(mx, s0[r]);
#pragma unroll
    for (int r = 0; r < 16; ++r) mx = fmaxf(mx, s1[r]);
    mx = fmaxf(mx, __shfl_xor(mx, 32));

    if (!__all(mx <= m + 11.0f)) {
      const float mn = fmaxf(m, mx);
      const float c = __builtin_amdgcn_exp2f(m - mn);
      m = mn;
      float cr[16];
#pragma unroll
      for (int r = 0; r < 16; ++r)
        cr[r] = __shfl(c, (r & 3) + 8 * (r >> 2) + 4 * l5);
#pragma unroll
      for (int r = 0; r < 16; ++r) {
        la[r] *= cr[r];
        o0[r] *= cr[r];
        o1[r] *= cr[r];
      }
    }

#pragma unroll
    for (int r = 0; r < 16; ++r) {
      s0[r] = __builtin_amdgcn_exp2f(s0[r] - m);
      s1[r] = __builtin_amdgcn_exp2f(s1[r] - m);
    }
    unsigned int u[16];
#pragma unroll
    for (int j = 0; j < 8; ++j) {
      CVTPK(u[j], s0[2 * j], s0[2 * j + 1]);
      CVTPK(u[8 + j], s1[2 * j], s1[2 * j + 1]);
    }
    PLSWAP(u[0], u[2]);
    PLSWAP(u[1], u[3]);
    PLSWAP(u[4], u[6]);
    PLSWAP(u[5], u[7]);
    PLSWAP(u[8], u[10]);
    PLSWAP(u[9], u[11]);
    PLSWAP(u[12], u[14]);
    PLSWAP(u[13], u[15]);
    short8 pa[4];
    {
      int4v t0 = {(int)u[0], (int)u[1], (int)u[2], (int)u[3]};
      int4v t1 = {(int)u[4], (int)u[5], (int)u[6], (int)u[7]};
      int4v t2 = {(int)u[8], (int)u[9], (int)u[10], (int)u[11]};
      int4v t3 = {(int)u[12], (int)u[13], (int)u[14], (int)u[15]};
      pa[0] = __builtin_bit_cast(short8, t0);
      pa[1] = __builtin_bit_cast(short8, t1);
      pa[2] = __builtin_bit_cast(short8, t2);
      pa[3] = __builtin_bit_cast(short8, t3);
    }

    const char* vB = (const char*)(&vbuf[buf][0]) + l31 * 128;
    const char* wB = (const char*)(&wbuf[0]) + kb * 128 + ko;
#pragma unroll
    for (int kk = 0; kk < 4; ++kk) {
      const int off = (kk * 32 + ko) ^ S3;
      short8 v0 = *reinterpret_cast<const short8*>(vB + off);
      short8 v1 = *reinterpret_cast<const short8*>(vB + 4096 + off);
      short8 wf = *reinterpret_cast<const short8*>(wB + kk * 32);
      o0 = MFMA32(pa[kk], v0, o0, 0, 0, 0);
      o1 = MFMA32(pa[kk], v1, o1, 0, 0, 0);
      la = MFMA32(pa[kk], wf, la, 0, 0, 0);
    }

    asm volatile("s_waitcnt vmcnt(0)" ::: "memory");
    __syncthreads();
    buf ^= 1;
  }

  const int qbase = b * 1024 + qb * 128 + w * 32;
#pragma unroll
  for (int r = 0; r < 16; ++r) {
    const float iv = __builtin_amdgcn_rcpf(la[r]);
    const int q = qbase + (r & 3) + 8 * (r >> 2) + 4 * l5;
    float* op = out + (size_t)q * 768 + h * 64 + l31;
    op[0] = o0[r] * iv;
    op[32] = o1[r] * iv;
  }
}

// ---------------------------------------------------------------------------
extern "C" void kernel_launch(void* const* d_in, const int* in_sizes, int n_in,
                              void* d_out, int out_size, void* d_ws,
                              size_t ws_size, hipStream_t stream) {
  const float* query = (const float*)d_in[0];
  const float* key = (const float*)d_in[1];
  const float* Wd = (const float*)d_in[2];
  const float* Wq = (const float*)d_in[3];
  const float* bq = (const float*)d_in[4];
  const float* Wk = (const float*)d_in[5];
  const float* bk = (const float*)d_in[6];
  const float* Wv = (const float*)d_in[7];
  const float* bv = (const float*)d_in[8];
  float* out = (float*)d_out;

  char* p = (char*)d_ws;
  auto alloc = [&](size_t n) {
    char* r = p;
    p += (n + 255) & ~(size_t)255;
    return r;
  };
  unsigned short* Xq = (unsigned short*)alloc(8192ULL * 768 * 2);
  unsigned short* Xk = (unsigned short*)alloc(8192ULL * 768 * 2);
  unsigned short* Wcq = (unsigned short*)alloc(1536ULL * 768 * 2);
  unsigned short* Wck = (unsigned short*)alloc(2304ULL * 768 * 2);
  unsigned short* Qc = (unsigned short*)alloc(96ULL * 1024 * 128 * 2);
  unsigned short* Kc = (unsigned short*)alloc(96ULL * 1024 * 128 * 2);
  unsigned short* Vt = (unsigned short*)alloc(96ULL * 64 * 1024 * 2);
  unsigned short* wqv = (unsigned short*)alloc(96ULL * 1024 * 2);
  // Vs aliases Xk: Xk is dead after proj_kernel; wv writes Vs before attn
  // reads it, and cvtx rewrites Xk at the start of every call.
  unsigned short* Vs = Xk;

  cvtx_kernel<<<12288, 256, 0, stream>>>(query, key, Xq, Xk);
  cvtw_kernel<<<2880, 256, 0, stream>>>(Wd, Wq, Wk, Wv, Wcq, Wck);

  proj_kernel<<<dim3(64, 30), 256, 0, stream>>>(Xq, Xk, Wcq, Wck, bq, bk, bv,
                                                Qc, Kc, Vt);

  wv_kernel<<<96, 256, 0, stream>>>(Kc, wqv, Vt, Vs);

  attn_kernel<<<768, 256, 0, stream>>>(Qc, Kc, Vs, wqv, out);
}

// Round 6
// 164.046 us; speedup vs baseline: 2.5206x; 1.0428x over previous
//
#include <hip/hip_runtime.h>
#include <stdint.h>

typedef __attribute__((ext_vector_type(8))) short short8;
typedef __attribute__((ext_vector_type(4))) short short4v;
typedef __attribute__((ext_vector_type(4))) float f32x4;
typedef __attribute__((ext_vector_type(16))) float f32x16;
typedef __attribute__((ext_vector_type(4))) int int4v;

static __device__ __forceinline__ unsigned short f2b(float f) {
  unsigned int u = __builtin_bit_cast(unsigned int, f);
  u += 0x7fffu + ((u >> 16) & 1u);
  return (unsigned short)(u >> 16);
}
static __device__ __forceinline__ float b2f(unsigned short b) {
  unsigned int u = ((unsigned int)b) << 16;
  return __builtin_bit_cast(float, u);
}

#define GLD16(gp, lp)                                                          \
  __builtin_amdgcn_global_load_lds(                                            \
      (const __attribute__((address_space(1))) void*)(gp),                     \
      (__attribute__((address_space(3))) void*)(lp), 16, 0, 0)

#define MFMA16 __builtin_amdgcn_mfma_f32_16x16x32_bf16
#define MFMA32 __builtin_amdgcn_mfma_f32_32x32x16_bf16

#define CVTPK(dst, lo, hi)                                                     \
  asm("v_cvt_pk_bf16_f32 %0, %1, %2" : "=v"(dst) : "v"(lo), "v"(hi))
#define PLSWAP(x, y)                                                           \
  asm volatile("v_permlane32_swap_b32 %0, %1" : "+v"(x), "+v"(y))

// QSC = 0.125 * log2(e); C2 = 0.0625 * log2(e)
#define QSC 0.18033688011112113f
#define C2 0.09016844005556057f

// ---------------- fp32 -> bf16 converts (fused launches) ------------------
__global__ void cvtx_kernel(const float* __restrict__ q,
                            const float* __restrict__ k,
                            unsigned short* __restrict__ Xq,
                            unsigned short* __restrict__ Xk) {
  const int bx = blockIdx.x;
  const bool lo = bx < 6144;
  const float* src = lo ? q : k;
  unsigned short* dst = lo ? Xq : Xk;
  const int i = (lo ? bx : bx - 6144) * 256 + threadIdx.x;
  float4 v = reinterpret_cast<const float4*>(src)[i];
  short4v o;
  o.x = (short)f2b(v.x);
  o.y = (short)f2b(v.y);
  o.z = (short)f2b(v.z);
  o.w = (short)f2b(v.w);
  reinterpret_cast<short4v*>(dst)[i] = o;
}

__global__ void cvtw_kernel(const float* __restrict__ Wd,
                            const float* __restrict__ Wq,
                            const float* __restrict__ Wk,
                            const float* __restrict__ Wv,
                            unsigned short* __restrict__ Wcq,
                            unsigned short* __restrict__ Wck) {
  const int bx = blockIdx.x;
  const int seg = bx / 576;
  const int i = (bx - seg * 576) * 256 + threadIdx.x;
  const float* src;
  unsigned short* dst;
  switch (seg) {
    case 0: src = Wd; dst = Wcq; break;
    case 1: src = Wq; dst = Wcq + 589824; break;
    case 2: src = Wd; dst = Wck; break;
    case 3: src = Wk; dst = Wck + 589824; break;
    default: src = Wv; dst = Wck + 1179648; break;
  }
  float4 v = reinterpret_cast<const float4*>(src)[i];
  short4v o;
  o.x = (short)f2b(v.x);
  o.y = (short)f2b(v.y);
  o.z = (short)f2b(v.z);
  o.w = (short)f2b(v.w);
  reinterpret_cast<short4v*>(dst)[i] = o;
}

// ---------------- fused projection GEMM (both inputs, one dispatch) -------
// grid (64, 30): by<12 -> query path (Xq x Wcq), else key path (Xk x Wck).
// 3-buffer LDS, 2-iteration-deep global_load_lds prefetch, counted
// s_waitcnt vmcnt(4) (T4): the barrier no longer drains in-flight loads.
// A/B tiles 16B-slot swizzled (slot ^= row&3) via pre-swizzled source.
__global__ __launch_bounds__(256) void proj_kernel(
    const unsigned short* __restrict__ Xq, const unsigned short* __restrict__ Xk,
    const unsigned short* __restrict__ Wcq, const unsigned short* __restrict__ Wck,
    const float* __restrict__ bq, const float* __restrict__ bk,
    const float* __restrict__ bv, unsigned short* __restrict__ Qc,
    unsigned short* __restrict__ Kc, unsigned short* __restrict__ Vt) {
  __shared__ __align__(16) short lds[3][2][128 * 32];  // 48 KB
  const int by = blockIdx.y;
  const bool mode0 = (by < 12);
  const unsigned short* X = mode0 ? Xq : Xk;
  const unsigned short* W = mode0 ? Wcq : Wck;
  const int col0 = (mode0 ? by : by - 12) * 128;
  const int row0 = blockIdx.x * 128;
  const int lane = threadIdx.x & 63;
  const int w = threadIdx.x >> 6;
  const int wr = w >> 1, wc = w & 1;
  const int l15 = lane & 15, l4 = lane >> 4;

  f32x4 acc[4][4];
#pragma unroll
  for (int i = 0; i < 4; ++i)
#pragma unroll
    for (int j = 0; j < 4; ++j) acc[i][j] = (f32x4){0.f, 0.f, 0.f, 0.f};

  auto stage = [&](int bufi, int k0) {
#pragma unroll
    for (int iss = 0; iss < 2; ++iss) {
      const int c = iss * 256 + w * 64 + lane;
      const int r = c >> 2;
      const int sl = (c & 3) ^ (r & 3);
      const unsigned short* gp = X + (size_t)(row0 + r) * 768 + k0 + sl * 8;
      GLD16(gp, (char*)&lds[bufi][0][0] + (iss * 256 + w * 64) * 16);
    }
#pragma unroll
    for (int iss = 0; iss < 2; ++iss) {
      const int c = iss * 256 + w * 64 + lane;
      const int r = c >> 2;
      const int sl = (c & 3) ^ (r & 3);
      const unsigned short* gp = W + (size_t)(col0 + r) * 768 + k0 + sl * 8;
      GLD16(gp, (char*)&lds[bufi][1][0] + (iss * 256 + w * 64) * 16);
    }
  };

  // 2-deep prologue: buffers 0 and 1 in flight (8 loads/wave outstanding)
  stage(0, 0);
  stage(1, 32);

#pragma unroll 3
  for (int kt = 0; kt < 24; ++kt) {
    // Wait until only the newest stage (4 loads) is outstanding -> buf kt done.
    if (kt < 23) {
      asm volatile("s_waitcnt vmcnt(4)" ::: "memory");
    } else {
      asm volatile("s_waitcnt vmcnt(0)" ::: "memory");
    }
    __syncthreads();  // all waves: buf kt loaded; done computing buf kt-1
    if (kt < 22) stage((kt + 2) % 3, (kt + 2) * 32);

    const char* Ab = (const char*)&lds[kt % 3][0][0];
    const char* Bb = (const char*)&lds[kt % 3][1][0];
    short8 a[4], b[4];
#pragma unroll
    for (int mt = 0; mt < 4; ++mt) {
      const int r = wr * 64 + mt * 16 + l15;
      a[mt] = *reinterpret_cast<const short8*>(Ab + r * 64 +
                                               ((l4 ^ (r & 3)) << 4));
    }
#pragma unroll
    for (int nt = 0; nt < 4; ++nt) {
      const int r = wc * 64 + nt * 16 + l15;
      b[nt] = *reinterpret_cast<const short8*>(Bb + r * 64 +
                                               ((l4 ^ (r & 3)) << 4));
    }
#pragma unroll
    for (int mt = 0; mt < 4; ++mt)
#pragma unroll
      for (int nt = 0; nt < 4; ++nt)
        acc[mt][nt] = MFMA16(a[mt], b[nt], acc[mt][nt], 0, 0, 0);
  }

  // ---- epilogue: direct scatter (replay-proven); Vt packs short4 ----
  const int mat = mode0 ? (col0 >= 768 ? 1 : 0) : (col0 / 768);
  const int cbase = col0 - mat * 768 + wc * 64;
  const float* barr = mode0 ? bq : (mat == 2 ? bv : bk);
  if (!mode0 && mat == 2) {
#pragma unroll
    for (int nt = 0; nt < 4; ++nt) {
      const int cc = cbase + nt * 16 + l15;
      const int hh = cc >> 6, dd = cc & 63;
      const float bias = barr[cc];
#pragma unroll
      for (int mt = 0; mt < 4; ++mt) {
        const int row = row0 + wr * 64 + mt * 16 + l4 * 4;
        const int bb = row >> 10, nn = row & 1023;
        short4v pv;
#pragma unroll
        for (int i = 0; i < 4; ++i)
          pv[i] = (short)f2b(acc[mt][nt][i] + bias);
        *reinterpret_cast<short4v*>(
            Vt + ((size_t)(bb * 12 + hh) * 64 + dd) * 1024 + nn) = pv;
      }
    }
  } else {
    const float scale = mode0 ? QSC : 1.0f;
    unsigned short* outC = mode0 ? Qc : Kc;
#pragma unroll
    for (int nt = 0; nt < 4; ++nt) {
      const int cc = cbase + nt * 16 + l15;
      const int hh = cc >> 6, dd = cc & 63;
      const float bias = (mat >= 1) ? barr[cc] : 0.f;
#pragma unroll
      for (int mt = 0; mt < 4; ++mt) {
#pragma unroll
        for (int i = 0; i < 4; ++i) {
          const int row = row0 + wr * 64 + mt * 16 + l4 * 4 + i;
          const int bb = row >> 10, nn = row & 1023;
          outC[((size_t)(bb * 12 + hh) * 1024 + nn) * 128 + mat * 64 + dd] =
              f2b((acc[mt][nt][i] + bias) * scale);
        }
      }
    }
  }
}

// ---------------- w = exp2(-|kd|^2*C2); Vs = Vt * w (no RMW) --------------
__global__ __launch_bounds__(256) void wv_kernel(
    const unsigned short* __restrict__ Kc, unsigned short* __restrict__ wq,
    const unsigned short* __restrict__ Vt, unsigned short* __restrict__ Vs) {
  __shared__ float wf[1024];
  const int bh = blockIdx.x;
  const int t = threadIdx.x;
  const int part = t & 3;
  const unsigned short* Kb = Kc + (size_t)bh * 1024 * 128;
#pragma unroll
  for (int it = 0; it < 16; ++it) {
    const int key = it * 64 + (t >> 2);
    const short8* p =
        reinterpret_cast<const short8*>(Kb + (size_t)key * 128 + part * 16);
    float s = 0.f;
    short8 x0 = p[0], x1 = p[1];
#pragma unroll
    for (int j = 0; j < 8; ++j) {
      const float f0 = b2f((unsigned short)x0[j]);
      const float f1 = b2f((unsigned short)x1[j]);
      s += f0 * f0 + f1 * f1;
    }
    s += __shfl_xor(s, 1);
    s += __shfl_xor(s, 2);
    if (part == 0) {
      const unsigned short wb = f2b(__builtin_amdgcn_exp2f(-s * C2));
      wf[key] = b2f(wb);  // bf16-rounded: consistent num/denominator
      wq[(size_t)bh * 1024 + key] = wb;
    }
  }
  __syncthreads();
  const unsigned short* Vb = Vt + (size_t)bh * 64 * 1024;
  unsigned short* Ob = Vs + (size_t)bh * 64 * 1024;
#pragma unroll
  for (int i = 0; i < 32; ++i) {
    const int e0 = (i * 256 + t) * 8;
    const int k0 = e0 & 1023;
    short8 v = *reinterpret_cast<const short8*>(Vb + e0);
#pragma unroll
    for (int j = 0; j < 8; ++j)
      v[j] = (short)f2b(b2f((unsigned short)v[j]) * wf[k0 + j]);
    *reinterpret_cast<short8*>(Ob + e0) = v;
  }
}

// ---------------- flash attention: swapped-QK 32x32, in-register softmax --
__global__ __launch_bounds__(256, 3) void attn_kernel(
    const unsigned short* __restrict__ Qc, const unsigned short* __restrict__ Kc,
    const unsigned short* __restrict__ Vs, const unsigned short* __restrict__ wq,
    float* __restrict__ out) {
  __shared__ __align__(16) short kbuf[2][64 * 128];  // 32 KB, swz (row&15)<<4
  __shared__ __align__(16) short vbuf[2][64 * 64];   // 16 KB, swz (row&7)<<4
  __shared__ __align__(16) short wbuf[1024];         // 2 KB

  const int bh = blockIdx.x % 96;
  const int qb = blockIdx.x / 96;
  const int b = bh / 12, h = bh - b * 12;
  const int lane = threadIdx.x & 63;
  const int w = threadIdx.x >> 6;
  const int l31 = lane & 31, l5 = lane >> 5;

  const unsigned short* Kg = Kc + (size_t)bh * 1024 * 128;
  const unsigned short* Vg = Vs + (size_t)bh * 64 * 1024;

  auto stageK = [&](int bufi, int kb) {
#pragma unroll
    for (int i = 0; i < 4; ++i) {
      const int slot = i * 256 + threadIdx.x;
      const int row = slot >> 4;
      const int d0 = ((slot & 15) ^ (row & 15)) * 8;
      const unsigned short* gp = Kg + (size_t)(kb * 64 + row) * 128 + d0;
      GLD16(gp, (char*)(&kbuf[bufi][0]) + (i * 256 + w * 64) * 16);
    }
  };
  auto stageV = [&](int bufi, int kb) {
#pragma unroll
    for (int i = 0; i < 2; ++i) {
      const int slot = i * 256 + threadIdx.x;
      const int row = slot >> 3;
      const int k0 = ((slot & 7) ^ (row & 7)) * 8;
      const unsigned short* gp = Vg + (size_t)row * 1024 + kb * 64 + k0;
      GLD16(gp, (char*)(&vbuf[bufi][0]) + (i * 256 + w * 64) * 16);
    }
  };

  stageK(0, 0);
  stageV(0, 0);
  if (w < 2) {
    const unsigned short* gp = wq + (size_t)bh * 1024 + (w * 64 + lane) * 8;
    GLD16(gp, (char*)(&wbuf[0]) + w * 1024);
  }

  const unsigned short* Qb =
      Qc + ((size_t)bh * 1024 + qb * 128 + w * 32 + l31) * 128 + l5 * 8;
  short8 qf[8];
#pragma unroll
  for (int s = 0; s < 8; ++s)
    qf[s] = *reinterpret_cast<const short8*>(Qb + s * 16);

  f32x16 o0, o1, la;
#pragma unroll
  for (int r = 0; r < 16; ++r) {
    o0[r] = 0.f;
    o1[r] = 0.f;
    la[r] = 0.f;
  }
  float m = -1e30f;

  const int S4 = (lane & 15) << 4;
  const int S3 = (lane & 7) << 4;
  const int ko = l5 * 16;

  asm volatile("s_waitcnt vmcnt(0)" ::: "memory");
  __syncthreads();

  int buf = 0;
  for (int kb = 0; kb < 16; ++kb) {
    if (kb < 15) {
      stageK(buf ^ 1, kb + 1);
      stageV(buf ^ 1, kb + 1);
    }

    const char* kB = (const char*)(&kbuf[buf][0]) + l31 * 256;
    f32x16 s0, s1;
#pragma unroll
    for (int r = 0; r < 16; ++r) {
      s0[r] = 0.f;
      s1[r] = 0.f;
    }
#pragma unroll
    for (int s = 0; s < 8; ++s) {
      const int off = (s * 32 + ko) ^ S4;
      short8 a0 = *reinterpret_cast<const short8*>(kB + off);
      short8 a1 = *reinterpret_cast<const short8*>(kB + 8192 + off);
      s0 = MFMA32(a0, qf[s], s0, 0, 0, 0);
      s1 = MFMA32(a1, qf[s], s1, 0, 0, 0);
    }

    float mx = s0[0];
#pragma unroll
    for (int r = 1; r < 16; ++r) mx = fmaxf(mx, s0[r]);
#pragma unroll
    for (int r = 0; r < 16; ++r) mx = fmaxf(mx, s1[r]);
    mx = fmaxf(mx, __shfl_xor(mx, 32));

    if (!__all(mx <= m + 11.0f)) {
      const float mn = fmaxf(m, mx);
      const float c = __builtin_amdgcn_exp2f(m - mn);
      m = mn;
      float cr[16];
#pragma unroll
      for (int r = 0; r < 16; ++r)
        cr[r] = __shfl(c, (r & 3) + 8 * (r >> 2) + 4 * l5);
#pragma unroll
      for (int r = 0; r < 16; ++r) {
        la[r] *= cr[r];
        o0[r] *= cr[r];
        o1[r] *= cr[r];
      }
    }

#pragma unroll
    for (int r = 0; r < 16; ++r) {
      s0[r] = __builtin_amdgcn_exp2f(s0[r] - m);
      s1[r] = __builtin_amdgcn_exp2f(s1[r] - m);
    }
    unsigned int u[16];
#pragma unroll
    for (int j = 0; j < 8; ++j) {
      CVTPK(u[j], s0[2 * j], s0[2 * j + 1]);
      CVTPK(u[8 + j], s1[2 * j], s1[2 * j + 1]);
    }
    PLSWAP(u[0], u[2]);
    PLSWAP(u[1], u[3]);
    PLSWAP(u[4], u[6]);
    PLSWAP(u[5], u[7]);
    PLSWAP(u[8], u[10]);
    PLSWAP(u[9], u[11]);
    PLSWAP(u[12], u[14]);
    PLSWAP(u[13], u[15]);
    short8 pa[4];
    {
      int4v t0 = {(int)u[0], (int)u[1], (int)u[2], (int)u[3]};
      int4v t1 = {(int)u[4], (int)u[5], (int)u[6], (int)u[7]};
      int4v t2 = {(int)u[8], (int)u[9], (int)u[10], (int)u[11]};
      int4v t3 = {(int)u[12], (int)u[13], (int)u[14], (int)u[15]};
      pa[0] = __builtin_bit_cast(short8, t0);
      pa[1] = __builtin_bit_cast(short8, t1);
      pa[2] = __builtin_bit_cast(short8, t2);
      pa[3] = __builtin_bit_cast(short8, t3);
    }

    const char* vB = (const char*)(&vbuf[buf][0]) + l31 * 128;
    const char* wB = (const char*)(&wbuf[0]) + kb * 128 + ko;
#pragma unroll
    for (int kk = 0; kk < 4; ++kk) {
      const int off = (kk * 32 + ko) ^ S3;
      short8 v0 = *reinterpret_cast<const short8*>(vB + off);
      short8 v1 = *reinterpret_cast<const short8*>(vB + 4096 + off);
      short8 wf = *reinterpret_cast<const short8*>(wB + kk * 32);
      o0 = MFMA32(pa[kk], v0, o0, 0, 0, 0);
      o1 = MFMA32(pa[kk], v1, o1, 0, 0, 0);
      la = MFMA32(pa[kk], wf, la, 0, 0, 0);
    }

    asm volatile("s_waitcnt vmcnt(0)" ::: "memory");
    __syncthreads();
    buf ^= 1;
  }

  const int qbase = b * 1024 + qb * 128 + w * 32;
#pragma unroll
  for (int r = 0; r < 16; ++r) {
    const float iv = __builtin_amdgcn_rcpf(la[r]);
    const int q = qbase + (r & 3) + 8 * (r >> 2) + 4 * l5;
    float* op = out + (size_t)q * 768 + h * 64 + l31;
    op[0] = o0[r] * iv;
    op[32] = o1[r] * iv;
  }
}

// ---------------------------------------------------------------------------
extern "C" void kernel_launch(void* const* d_in, const int* in_sizes, int n_in,
                              void* d_out, int out_size, void* d_ws,
                              size_t ws_size, hipStream_t stream) {
  const float* query = (const float*)d_in[0];
  const float* key = (const float*)d_in[1];
  const float* Wd = (const float*)d_in[2];
  const float* Wq = (const float*)d_in[3];
  const float* bq = (const float*)d_in[4];
  const float* Wk = (const float*)d_in[5];
  const float* bk = (const float*)d_in[6];
  const float* Wv = (const float*)d_in[7];
  const float* bv = (const float*)d_in[8];
  float* out = (float*)d_out;

  char* p = (char*)d_ws;
  auto alloc = [&](size_t n) {
    char* r = p;
    p += (n + 255) & ~(size_t)255;
    return r;
  };
  unsigned short* Xq = (unsigned short*)alloc(8192ULL * 768 * 2);
  unsigned short* Xk = (unsigned short*)alloc(8192ULL * 768 * 2);
  unsigned short* Wcq = (unsigned short*)alloc(1536ULL * 768 * 2);
  unsigned short* Wck = (unsigned short*)alloc(2304ULL * 768 * 2);
  unsigned short* Qc = (unsigned short*)alloc(96ULL * 1024 * 128 * 2);
  unsigned short* Kc = (unsigned short*)alloc(96ULL * 1024 * 128 * 2);
  unsigned short* Vt = (unsigned short*)alloc(96ULL * 64 * 1024 * 2);
  unsigned short* wqv = (unsigned short*)alloc(96ULL * 1024 * 2);
  // Vs aliases Xk: Xk is dead after proj_kernel; wv writes Vs before attn
  // reads it, and cvtx rewrites Xk at the start of every call.
  unsigned short* Vs = Xk;

  cvtx_kernel<<<12288, 256, 0, stream>>>(query, key, Xq, Xk);
  cvtw_kernel<<<2880, 256, 0, stream>>>(Wd, Wq, Wk, Wv, Wcq, Wck);

  proj_kernel<<<dim3(64, 30), 256, 0, stream>>>(Xq, Xk, Wcq, Wck, bq, bk, bv,
                                                Qc, Kc, Vt);

  wv_kernel<<<96, 256, 0, stream>>>(Kc, wqv, Vt, Vs);

  attn_kernel<<<768, 256, 0, stream>>>(Qc, Kc, Vs, wqv, out);
}

// Round 7
// 155.006 us; speedup vs baseline: 2.6676x; 1.0583x over previous
//
#include <hip/hip_runtime.h>
#include <stdint.h>

typedef __attribute__((ext_vector_type(8))) short short8;
typedef __attribute__((ext_vector_type(4))) short short4v;
typedef __attribute__((ext_vector_type(4))) float f32x4;
typedef __attribute__((ext_vector_type(16))) float f32x16;
typedef __attribute__((ext_vector_type(4))) int int4v;

static __device__ __forceinline__ unsigned short f2b(float f) {
  unsigned int u = __builtin_bit_cast(unsigned int, f);
  u += 0x7fffu + ((u >> 16) & 1u);
  return (unsigned short)(u >> 16);
}
static __device__ __forceinline__ float b2f(unsigned short b) {
  unsigned int u = ((unsigned int)b) << 16;
  return __builtin_bit_cast(float, u);
}

#define GLD16(gp, lp)                                                          \
  __builtin_amdgcn_global_load_lds(                                            \
      (const __attribute__((address_space(1))) void*)(gp),                     \
      (__attribute__((address_space(3))) void*)(lp), 16, 0, 0)

#define MFMA16 __builtin_amdgcn_mfma_f32_16x16x32_bf16
#define MFMA32 __builtin_amdgcn_mfma_f32_32x32x16_bf16

#define CVTPK(dst, lo, hi)                                                     \
  asm("v_cvt_pk_bf16_f32 %0, %1, %2" : "=v"(dst) : "v"(lo), "v"(hi))
#define PLSWAP(x, y)                                                           \
  asm volatile("v_permlane32_swap_b32 %0, %1" : "+v"(x), "+v"(y))

// QSC = 0.125 * log2(e); C2 = 0.0625 * log2(e)
#define QSC 0.18033688011112113f
#define C2 0.09016844005556057f

// ---------------- fp32 -> bf16 converts (fused launches) ------------------
__global__ void cvtx_kernel(const float* __restrict__ q,
                            const float* __restrict__ k,
                            unsigned short* __restrict__ Xq,
                            unsigned short* __restrict__ Xk) {
  const int bx = blockIdx.x;
  const bool lo = bx < 6144;
  const float* src = lo ? q : k;
  unsigned short* dst = lo ? Xq : Xk;
  const int i = (lo ? bx : bx - 6144) * 256 + threadIdx.x;
  float4 v = reinterpret_cast<const float4*>(src)[i];
  short4v o;
  o.x = (short)f2b(v.x);
  o.y = (short)f2b(v.y);
  o.z = (short)f2b(v.z);
  o.w = (short)f2b(v.w);
  reinterpret_cast<short4v*>(dst)[i] = o;
}

__global__ void cvtw_kernel(const float* __restrict__ Wd,
                            const float* __restrict__ Wq,
                            const float* __restrict__ Wk,
                            const float* __restrict__ Wv,
                            unsigned short* __restrict__ Wcq,
                            unsigned short* __restrict__ Wck) {
  const int bx = blockIdx.x;
  const int seg = bx / 576;
  const int i = (bx - seg * 576) * 256 + threadIdx.x;
  const float* src;
  unsigned short* dst;
  switch (seg) {
    case 0: src = Wd; dst = Wcq; break;
    case 1: src = Wq; dst = Wcq + 589824; break;
    case 2: src = Wd; dst = Wck; break;
    case 3: src = Wk; dst = Wck + 589824; break;
    default: src = Wv; dst = Wck + 1179648; break;
  }
  float4 v = reinterpret_cast<const float4*>(src)[i];
  short4v o;
  o.x = (short)f2b(v.x);
  o.y = (short)f2b(v.y);
  o.z = (short)f2b(v.z);
  o.w = (short)f2b(v.w);
  reinterpret_cast<short4v*>(dst)[i] = o;
}

// ---------------- fused projection GEMM: 256x256 tile, 8 waves ------------
// grid (32, 15): by<6 -> query path (Xq x Wcq), else key path (Xk x Wck).
// 3-buffer LDS (96 KB), 2-deep global_load_lds prefetch, counted
// s_waitcnt vmcnt(4) + RAW s_barrier (no compiler vmcnt(0) drain).
// 16B-slot swizzle: slot ^= (row>>1)&3 on both staging source and reads
// -> 16 lanes spread over all 8 bank-quads (2/quad = conflict-free).
__global__ __launch_bounds__(512, 2) void proj_kernel(
    const unsigned short* __restrict__ Xq, const unsigned short* __restrict__ Xk,
    const unsigned short* __restrict__ Wcq, const unsigned short* __restrict__ Wck,
    const float* __restrict__ bq, const float* __restrict__ bk,
    const float* __restrict__ bv, unsigned short* __restrict__ Qc,
    unsigned short* __restrict__ Kc, unsigned short* __restrict__ Vt) {
  __shared__ __align__(16) short lds[3][2][256 * 32];  // 96 KB
  const int by = blockIdx.y;
  const bool mode0 = (by < 6);
  const unsigned short* X = mode0 ? Xq : Xk;
  const unsigned short* W = mode0 ? Wcq : Wck;
  const int col0 = (mode0 ? by : by - 6) * 256;
  const int row0 = blockIdx.x * 256;
  const int tid = threadIdx.x;
  const int lane = tid & 63;
  const int wid = tid >> 6;          // 0..7
  const int wm = wid >> 2;           // 0..1 (M)
  const int wn = wid & 3;            // 0..3 (N)
  const int l15 = lane & 15, l4 = lane >> 4;
  // lane-constant read swizzle term: (row>>1)&3 == (l15>>1)&3 (row base %16==0)
  const int RSWZ = (l4 ^ ((l15 >> 1) & 3)) << 4;

  f32x4 acc[8][4];
#pragma unroll
  for (int i = 0; i < 8; ++i)
#pragma unroll
    for (int j = 0; j < 4; ++j) acc[i][j] = (f32x4){0.f, 0.f, 0.f, 0.f};

  auto stage = [&](int bufi, int k0) {
    // A half: 256 rows x 32 cols = 1024 16B-slots; B half same.
#pragma unroll
    for (int iss = 0; iss < 2; ++iss) {
      const int c = iss * 512 + tid;
      const int r = c >> 2;
      const int sl = (c & 3) ^ ((c >> 3) & 3);  // == (c&3)^((r>>1)&3)
      const unsigned short* gp = X + (size_t)(row0 + r) * 768 + k0 + sl * 8;
      GLD16(gp, (char*)&lds[bufi][0][0] + (size_t)c * 16);
    }
#pragma unroll
    for (int iss = 0; iss < 2; ++iss) {
      const int c = iss * 512 + tid;
      const int r = c >> 2;
      const int sl = (c & 3) ^ ((c >> 3) & 3);
      const unsigned short* gp = W + (size_t)(col0 + r) * 768 + k0 + sl * 8;
      GLD16(gp, (char*)&lds[bufi][1][0] + (size_t)c * 16);
    }
  };

  // 2-deep prologue: 8 loads/wave outstanding
  stage(0, 0);
  stage(1, 32);

#pragma unroll 3
  for (int kt = 0; kt < 24; ++kt) {
    // Allow only the newest stage (4 loads) outstanding -> buf kt landed.
    if (kt < 23) {
      asm volatile("s_waitcnt vmcnt(4) lgkmcnt(0)" ::: "memory");
    } else {
      asm volatile("s_waitcnt vmcnt(0) lgkmcnt(0)" ::: "memory");
    }
    __builtin_amdgcn_s_barrier();
    asm volatile("" ::: "memory");
    if (kt < 22) stage((kt + 2) % 3, (kt + 2) * 32);

    const char* Ab = (const char*)&lds[kt % 3][0][0];
    const char* Bb = (const char*)&lds[kt % 3][1][0];
    short8 a[8], b[4];
#pragma unroll
    for (int mt = 0; mt < 8; ++mt) {
      const int r = wm * 128 + mt * 16 + l15;
      a[mt] = *reinterpret_cast<const short8*>(Ab + r * 64 + RSWZ);
    }
#pragma unroll
    for (int nt = 0; nt < 4; ++nt) {
      const int r = wn * 64 + nt * 16 + l15;
      b[nt] = *reinterpret_cast<const short8*>(Bb + r * 64 + RSWZ);
    }
#pragma unroll
    for (int mt = 0; mt < 8; ++mt)
#pragma unroll
      for (int nt = 0; nt < 4; ++nt)
        acc[mt][nt] = MFMA16(a[mt], b[nt], acc[mt][nt], 0, 0, 0);
  }

  // ---- epilogue: direct scatter (replay-proven); Vt packs short4 ----
  const int mat = mode0 ? (col0 >= 768 ? 1 : 0) : ((by - 6) / 3);
  const int cbase = col0 - mat * 768 + wn * 64;
  const float* barr = mode0 ? bq : (mat == 2 ? bv : bk);
  if (!mode0 && mat == 2) {
#pragma unroll
    for (int nt = 0; nt < 4; ++nt) {
      const int cc = cbase + nt * 16 + l15;
      const int hh = cc >> 6, dd = cc & 63;
      const float bias = barr[cc];
#pragma unroll
      for (int mt = 0; mt < 8; ++mt) {
        const int row = row0 + wm * 128 + mt * 16 + l4 * 4;
        const int bb = row >> 10, nn = row & 1023;
        short4v pv;
#pragma unroll
        for (int i = 0; i < 4; ++i)
          pv[i] = (short)f2b(acc[mt][nt][i] + bias);
        *reinterpret_cast<short4v*>(
            Vt + ((size_t)(bb * 12 + hh) * 64 + dd) * 1024 + nn) = pv;
      }
    }
  } else {
    const float scale = mode0 ? QSC : 1.0f;
    unsigned short* outC = mode0 ? Qc : Kc;
#pragma unroll
    for (int nt = 0; nt < 4; ++nt) {
      const int cc = cbase + nt * 16 + l15;
      const int hh = cc >> 6, dd = cc & 63;
      const float bias = (mat >= 1) ? barr[cc] : 0.f;
#pragma unroll
      for (int mt = 0; mt < 8; ++mt) {
#pragma unroll
        for (int i = 0; i < 4; ++i) {
          const int row = row0 + wm * 128 + mt * 16 + l4 * 4 + i;
          const int bb = row >> 10, nn = row & 1023;
          outC[((size_t)(bb * 12 + hh) * 1024 + nn) * 128 + mat * 64 + dd] =
              f2b((acc[mt][nt][i] + bias) * scale);
        }
      }
    }
  }
}

// ---------------- w = exp2(-|kd|^2*C2); Vs = Vt * w (no RMW) --------------
__global__ __launch_bounds__(256) void wv_kernel(
    const unsigned short* __restrict__ Kc, unsigned short* __restrict__ wq,
    const unsigned short* __restrict__ Vt, unsigned short* __restrict__ Vs) {
  __shared__ float wf[1024];
  const int bh = blockIdx.x;
  const int t = threadIdx.x;
  const int part = t & 3;
  const unsigned short* Kb = Kc + (size_t)bh * 1024 * 128;
#pragma unroll
  for (int it = 0; it < 16; ++it) {
    const int key = it * 64 + (t >> 2);
    const short8* p =
        reinterpret_cast<const short8*>(Kb + (size_t)key * 128 + part * 16);
    float s = 0.f;
    short8 x0 = p[0], x1 = p[1];
#pragma unroll
    for (int j = 0; j < 8; ++j) {
      const float f0 = b2f((unsigned short)x0[j]);
      const float f1 = b2f((unsigned short)x1[j]);
      s += f0 * f0 + f1 * f1;
    }
    s += __shfl_xor(s, 1);
    s += __shfl_xor(s, 2);
    if (part == 0) {
      const unsigned short wb = f2b(__builtin_amdgcn_exp2f(-s * C2));
      wf[key] = b2f(wb);  // bf16-rounded: consistent num/denominator
      wq[(size_t)bh * 1024 + key] = wb;
    }
  }
  __syncthreads();
  const unsigned short* Vb = Vt + (size_t)bh * 64 * 1024;
  unsigned short* Ob = Vs + (size_t)bh * 64 * 1024;
#pragma unroll
  for (int i = 0; i < 32; ++i) {
    const int e0 = (i * 256 + t) * 8;
    const int k0 = e0 & 1023;
    short8 v = *reinterpret_cast<const short8*>(Vb + e0);
#pragma unroll
    for (int j = 0; j < 8; ++j)
      v[j] = (short)f2b(b2f((unsigned short)v[j]) * wf[k0 + j]);
    *reinterpret_cast<short8*>(Ob + e0) = v;
  }
}

// ---------------- flash attention: swapped-QK 32x32, in-register softmax --
__global__ __launch_bounds__(256, 3) void attn_kernel(
    const unsigned short* __restrict__ Qc, const unsigned short* __restrict__ Kc,
    const unsigned short* __restrict__ Vs, const unsigned short* __restrict__ wq,
    float* __restrict__ out) {
  __shared__ __align__(16) short kbuf[2][64 * 128];  // 32 KB, swz (row&15)<<4
  __shared__ __align__(16) short vbuf[2][64 * 64];   // 16 KB, swz (row&7)<<4
  __shared__ __align__(16) short wbuf[1024];         // 2 KB

  const int bh = blockIdx.x % 96;
  const int qb = blockIdx.x / 96;
  const int b = bh / 12, h = bh - b * 12;
  const int lane = threadIdx.x & 63;
  const int w = threadIdx.x >> 6;
  const int l31 = lane & 31, l5 = lane >> 5;

  const unsigned short* Kg = Kc + (size_t)bh * 1024 * 128;
  const unsigned short* Vg = Vs + (size_t)bh * 64 * 1024;

  auto stageK = [&](int bufi, int kb) {
#pragma unroll
    for (int i = 0; i < 4; ++i) {
      const int slot = i * 256 + threadIdx.x;
      const int row = slot >> 4;
      const int d0 = ((slot & 15) ^ (row & 15)) * 8;
      const unsigned short* gp = Kg + (size_t)(kb * 64 + row) * 128 + d0;
      GLD16(gp, (char*)(&kbuf[bufi][0]) + (i * 256 + w * 64) * 16);
    }
  };
  auto stageV = [&](int bufi, int kb) {
#pragma unroll
    for (int i = 0; i < 2; ++i) {
      const int slot = i * 256 + threadIdx.x;
      const int row = slot >> 3;
      const int k0 = ((slot & 7) ^ (row & 7)) * 8;
      const unsigned short* gp = Vg + (size_t)row * 1024 + kb * 64 + k0;
      GLD16(gp, (char*)(&vbuf[bufi][0]) + (i * 256 + w * 64) * 16);
    }
  };

  stageK(0, 0);
  stageV(0, 0);
  if (w < 2) {
    const unsigned short* gp = wq + (size_t)bh * 1024 + (w * 64 + lane) * 8;
    GLD16(gp, (char*)(&wbuf[0]) + w * 1024);
  }

  const unsigned short* Qb =
      Qc + ((size_t)bh * 1024 + qb * 128 + w * 32 + l31) * 128 + l5 * 8;
  short8 qf[8];
#pragma unroll
  for (int s = 0; s < 8; ++s)
    qf[s] = *reinterpret_cast<const short8*>(Qb + s * 16);

  f32x16 o0, o1, la;
#pragma unroll
  for (int r = 0; r < 16; ++r) {
    o0[r] = 0.f;
    o1[r] = 0.f;
    la[r] = 0.f;
  }
  float m = -1e30f;

  const int S4 = (lane & 15) << 4;
  const int S3 = (lane & 7) << 4;
  const int ko = l5 * 16;

  asm volatile("s_waitcnt vmcnt(0)" ::: "memory");
  __syncthreads();

  int buf = 0;
  for (int kb = 0; kb < 16; ++kb) {
    if (kb < 15) {
      stageK(buf ^ 1, kb + 1);
      stageV(buf ^ 1, kb + 1);
    }

    const char* kB = (const char*)(&kbuf[buf][0]) + l31 * 256;
    f32x16 s0, s1;
#pragma unroll
    for (int r = 0; r < 16; ++r) {
      s0[r] = 0.f;
      s1[r] = 0.f;
    }
#pragma unroll
    for (int s = 0; s < 8; ++s) {
      const int off = (s * 32 + ko) ^ S4;
      short8 a0 = *reinterpret_cast<const short8*>(kB + off);
      short8 a1 = *reinterpret_cast<const short8*>(kB + 8192 + off);
      s0 = MFMA32(a0, qf[s], s0, 0, 0, 0);
      s1 = MFMA32(a1, qf[s], s1, 0, 0, 0);
    }

    float mx = s0[0];
#pragma unroll
    for (int r = 1; r < 16; ++r) mx = fmaxf(mx, s0[r]);
#pragma unroll
    for (int r = 0; r < 16; ++r) mx = fmaxf(mx, s1[r]);
    mx = fmaxf(mx, __shfl_xor(mx, 32));

    if (!__all(mx <= m + 11.0f)) {
      const float mn = fmaxf(m, mx);
      const float c = __builtin_amdgcn_exp2f(m - mn);
      m = mn;
      float cr[16];
#pragma unroll
      for (int r = 0; r < 16; ++r)
        cr[r] = __shfl(c, (r & 3) + 8 * (r >> 2) + 4 * l5);
#pragma unroll
      for (int r = 0; r < 16; ++r) {
        la[r] *= cr[r];
        o0[r] *= cr[r];
        o1[r] *= cr[r];
      }
    }

#pragma unroll
    for (int r = 0; r < 16; ++r) {
      s0[r] = __builtin_amdgcn_exp2f(s0[r] - m);
      s1[r] = __builtin_amdgcn_exp2f(s1[r] - m);
    }
    unsigned int u[16];
#pragma unroll
    for (int j = 0; j < 8; ++j) {
      CVTPK(u[j], s0[2 * j], s0[2 * j + 1]);
      CVTPK(u[8 + j], s1[2 * j], s1[2 * j + 1]);
    }
    PLSWAP(u[0], u[2]);
    PLSWAP(u[1], u[3]);
    PLSWAP(u[4], u[6]);
    PLSWAP(u[5], u[7]);
    PLSWAP(u[8], u[10]);
    PLSWAP(u[9], u[11]);
    PLSWAP(u[12], u[14]);
    PLSWAP(u[13], u[15]);
    short8 pa[4];
    {
      int4v t0 = {(int)u[0], (int)u[1], (int)u[2], (int)u[3]};
      int4v t1 = {(int)u[4], (int)u[5], (int)u[6], (int)u[7]};
      int4v t2 = {(int)u[8], (int)u[9], (int)u[10], (int)u[11]};
      int4v t3 = {(int)u[12], (int)u[13], (int)u[14], (int)u[15]};
      pa[0] = __builtin_bit_cast(short8, t0);
      pa[1] = __builtin_bit_cast(short8, t1);
      pa[2] = __builtin_bit_cast(short8, t2);
      pa[3] = __builtin_bit_cast(short8, t3);
    }

    const char* vB = (const char*)(&vbuf[buf][0]) + l31 * 128;
    const char* wB = (const char*)(&wbuf[0]) + kb * 128 + ko;
#pragma unroll
    for (int kk = 0; kk < 4; ++kk) {
      const int off = (kk * 32 + ko) ^ S3;
      short8 v0 = *reinterpret_cast<const short8*>(vB + off);
      short8 v1 = *reinterpret_cast<const short8*>(vB + 4096 + off);
      short8 wf = *reinterpret_cast<const short8*>(wB + kk * 32);
      o0 = MFMA32(pa[kk], v0, o0, 0, 0, 0);
      o1 = MFMA32(pa[kk], v1, o1, 0, 0, 0);
      la = MFMA32(pa[kk], wf, la, 0, 0, 0);
    }

    asm volatile("s_waitcnt vmcnt(0)" ::: "memory");
    __syncthreads();
    buf ^= 1;
  }

  const int qbase = b * 1024 + qb * 128 + w * 32;
#pragma unroll
  for (int r = 0; r < 16; ++r) {
    const float iv = __builtin_amdgcn_rcpf(la[r]);
    const int q = qbase + (r & 3) + 8 * (r >> 2) + 4 * l5;
    float* op = out + (size_t)q * 768 + h * 64 + l31;
    op[0] = o0[r] * iv;
    op[32] = o1[r] * iv;
  }
}

// ---------------------------------------------------------------------------
extern "C" void kernel_launch(void* const* d_in, const int* in_sizes, int n_in,
                              void* d_out, int out_size, void* d_ws,
                              size_t ws_size, hipStream_t stream) {
  const float* query = (const float*)d_in[0];
  const float* key = (const float*)d_in[1];
  const float* Wd = (const float*)d_in[2];
  const float* Wq = (const float*)d_in[3];
  const float* bq = (const float*)d_in[4];
  const float* Wk = (const float*)d_in[5];
  const float* bk = (const float*)d_in[6];
  const float* Wv = (const float*)d_in[7];
  const float* bv = (const float*)d_in[8];
  float* out = (float*)d_out;

  char* p = (char*)d_ws;
  auto alloc = [&](size_t n) {
    char* r = p;
    p += (n + 255) & ~(size_t)255;
    return r;
  };
  unsigned short* Xq = (unsigned short*)alloc(8192ULL * 768 * 2);
  unsigned short* Xk = (unsigned short*)alloc(8192ULL * 768 * 2);
  unsigned short* Wcq = (unsigned short*)alloc(1536ULL * 768 * 2);
  unsigned short* Wck = (unsigned short*)alloc(2304ULL * 768 * 2);
  unsigned short* Qc = (unsigned short*)alloc(96ULL * 1024 * 128 * 2);
  unsigned short* Kc = (unsigned short*)alloc(96ULL * 1024 * 128 * 2);
  unsigned short* Vt = (unsigned short*)alloc(96ULL * 64 * 1024 * 2);
  unsigned short* wqv = (unsigned short*)alloc(96ULL * 1024 * 2);
  // Vs aliases Xk: Xk is dead after proj_kernel; wv writes Vs before attn
  // reads it, and cvtx rewrites Xk at the start of every call.
  unsigned short* Vs = Xk;

  cvtx_kernel<<<12288, 256, 0, stream>>>(query, key, Xq, Xk);
  cvtw_kernel<<<2880, 256, 0, stream>>>(Wd, Wq, Wk, Wv, Wcq, Wck);

  proj_kernel<<<dim3(32, 15), 512, 0, stream>>>(Xq, Xk, Wcq, Wck, bq, bk, bv,
                                                Qc, Kc, Vt);

  wv_kernel<<<96, 256, 0, stream>>>(Kc, wqv, Vt, Vs);

  attn_kernel<<<768, 256, 0, stream>>>(Qc, Kc, Vs, wqv, out);
}